// Round 1
// baseline (1930.718 us; speedup 1.0000x reference)
//
#include <hip/hip_runtime.h>
#include <math.h>

// ---- problem constants ----
#define BB 2
#define DD 256
#define NH 8
#define DH 32
#define NPNP 4
#define LV 4
#define NQ 4096
#define NL 6
#define DFF 1024
#define SS 21760   // 128*128 + 64*64 + 32*32 + 16*16

// level dims/starts
__device__ __constant__ int c_dims[4]   = {128, 64, 32, 16};
__device__ __constant__ int c_starts[4] = {0, 16384, 20480, 21504};

// ------------------------------------------------------------------
// flatten: src (B, D, H, W) -> src_flat (B, S, D) at level offset
// 64x64 LDS transpose tile
// ------------------------------------------------------------------
__global__ __launch_bounds__(256) void flatten_kernel(
    const float* __restrict__ src, float* __restrict__ dst, int HW, int start)
{
    __shared__ float tile[64][65];
    const int b  = blockIdx.z;
    const int d0 = blockIdx.y * 64;
    const int s0 = blockIdx.x * 64;
    const int t  = threadIdx.x;
    const float* sp = src + ((size_t)b * DD + d0) * (size_t)HW + s0;
#pragma unroll
    for (int i = 0; i < 16; ++i) {
        int lin = i * 256 + t;
        int dl = lin >> 6, sl = lin & 63;
        tile[sl][dl] = sp[(size_t)dl * HW + sl];
    }
    __syncthreads();
    float* dp = dst + ((size_t)b * SS + start + s0) * DD + d0;
#pragma unroll
    for (int i = 0; i < 16; ++i) {
        int lin = i * 256 + t;
        int sl = lin >> 6, dl = lin & 63;
        dp[(size_t)sl * DD + dl] = tile[sl][dl];
    }
}

// ------------------------------------------------------------------
// generic f32 NT GEMM: out[r,e] = sum_d A[r,d]*W[e,d] + bias[e]
// BM=BN=64, BK=32, 256 threads, each 4x4 outputs
// ------------------------------------------------------------------
enum { EPI_PLAIN = 0, EPI_RELU = 1, EPI_RES = 2, EPI_VSC = 3 };

template <int K, int EPI>
__global__ __launch_bounds__(256) void gemm_nt(
    const float* __restrict__ A, const float* __restrict__ W,
    const float* __restrict__ bias, const float* __restrict__ res,
    float* __restrict__ out, int E)
{
    __shared__ float As[32][68];
    __shared__ float Ws[32][68];
    const int t = threadIdx.x;
    const size_t r0 = (size_t)blockIdx.x * 64;
    const int e0 = blockIdx.y * 64;
    const int tr = (t >> 4) << 2;
    const int tc = (t & 15) << 2;
    float acc[4][4] = {};
    const float* Ap = A + r0 * K;
    const float* Wp = W + (size_t)e0 * K;

    for (int k0 = 0; k0 < K; k0 += 32) {
#pragma unroll
        for (int i = 0; i < 2; ++i) {
            int lin = i * 256 + t;
            int rr = lin >> 3;
            int c4 = (lin & 7) << 2;
            float4 a4 = *(const float4*)(Ap + (size_t)rr * K + k0 + c4);
            As[c4 + 0][rr] = a4.x; As[c4 + 1][rr] = a4.y;
            As[c4 + 2][rr] = a4.z; As[c4 + 3][rr] = a4.w;
            float4 w4 = *(const float4*)(Wp + (size_t)rr * K + k0 + c4);
            Ws[c4 + 0][rr] = w4.x; Ws[c4 + 1][rr] = w4.y;
            Ws[c4 + 2][rr] = w4.z; Ws[c4 + 3][rr] = w4.w;
        }
        __syncthreads();
#pragma unroll
        for (int k = 0; k < 32; ++k) {
            float4 a4 = *(const float4*)&As[k][tr];
            float4 b4 = *(const float4*)&Ws[k][tc];
            float av[4] = {a4.x, a4.y, a4.z, a4.w};
            float bv[4] = {b4.x, b4.y, b4.z, b4.w};
#pragma unroll
            for (int m = 0; m < 4; ++m)
#pragma unroll
                for (int n = 0; n < 4; ++n)
                    acc[m][n] = fmaf(av[m], bv[n], acc[m][n]);
        }
        __syncthreads();
    }

#pragma unroll
    for (int m = 0; m < 4; ++m) {
        size_t r = r0 + tr + m;
        float v[4];
#pragma unroll
        for (int n = 0; n < 4; ++n) {
            float val = acc[m][n] + bias[e0 + tc + n];
            if (EPI == EPI_RELU) val = fmaxf(val, 0.f);
            v[n] = val;
        }
        if (EPI == EPI_RES) {
            float4 rr = *(const float4*)&res[r * E + e0 + tc];
            v[0] += rr.x; v[1] += rr.y; v[2] += rr.z; v[3] += rr.w;
        }
        float4 o4 = make_float4(v[0], v[1], v[2], v[3]);
        if (EPI == EPI_VSC) {
            int b = (int)(r / SS), s = (int)(r % SS);
            int e = e0 + tc;
            *(float4*)&out[(((size_t)b * NH + (e >> 5)) * SS + s) * DH + (e & 31)] = o4;
        } else {
            *(float4*)&out[r * E + e0 + tc] = o4;
        }
    }
}

// ------------------------------------------------------------------
// softmax over rows of 16 (in place)
// ------------------------------------------------------------------
__global__ __launch_bounds__(256) void softmax16(float* __restrict__ aw)
{
    int i = blockIdx.x * 256 + threadIdx.x;
    float* p = aw + (size_t)i * 16;
    float m = -1e30f;
#pragma unroll
    for (int j = 0; j < 16; ++j) m = fmaxf(m, p[j]);
    float s = 0.f;
    float e[16];
#pragma unroll
    for (int j = 0; j < 16; ++j) { e[j] = expf(p[j] - m); s += e[j]; }
    float inv = 1.f / s;
#pragma unroll
    for (int j = 0; j < 16; ++j) p[j] = e[j] * inv;
}

// ------------------------------------------------------------------
// MSDA sampling + aggregation.
// 32-lane group per (b,q,h); lane = dh.
// v: (B, NH, S, DH); offs: (B,NQ,NH,LV,NP,2); aw: (B,NQ,NH,LV,NP) softmaxed
// out: (B, NQ, D)
// ------------------------------------------------------------------
__global__ __launch_bounds__(256) void msda_kernel(
    const float* __restrict__ v, const float* __restrict__ offs,
    const float* __restrict__ aw, const float* __restrict__ qref,
    float* __restrict__ out)
{
    int gid = blockIdx.x * 8 + (threadIdx.x >> 5);
    int dh = threadIdx.x & 31;
    int h = gid & 7;
    int q = (gid >> 3) & (NQ - 1);
    int b = gid >> 15;
    size_t bq = (size_t)b * NQ + q;
    const float* vb = v + ((size_t)b * NH + h) * (size_t)SS * DH;
    float rx = qref[bq * 2 + 0];
    float ry = qref[bq * 2 + 1];
    const float* op = offs + (bq * NH + h) * (LV * NPNP * 2);
    const float* ap = aw + (bq * NH + h) * (LV * NPNP);
    float acc = 0.f;
#pragma unroll
    for (int l = 0; l < LV; ++l) {
        const int Wl = c_dims[l];
        const int st = c_starts[l];
        const float fW = (float)Wl;
#pragma unroll
        for (int p = 0; p < NPNP; ++p) {
            float a = ap[l * NPNP + p];
            float x = fmaf(rx, fW, op[(l * NPNP + p) * 2 + 0]) - 0.5f;
            float y = fmaf(ry, fW, op[(l * NPNP + p) * 2 + 1]) - 0.5f;
            float x0f = floorf(x), y0f = floorf(y);
            float wx = x - x0f, wy = y - y0f;
            int x0 = (int)x0f, y0 = (int)y0f;
#pragma unroll
            for (int c = 0; c < 4; ++c) {
                int dx = c & 1, dy = c >> 1;
                int xc = x0 + dx, yc = y0 + dy;
                bool valid = (xc >= 0) & (xc < Wl) & (yc >= 0) & (yc < Wl);
                int xi = min(max(xc, 0), Wl - 1);
                int yi = min(max(yc, 0), Wl - 1);
                float w = (dx ? wx : 1.f - wx) * (dy ? wy : 1.f - wy);
                float g = vb[((size_t)(st + yi * Wl + xi)) * DH + dh];
                float cw = valid ? (a * w) : 0.f;
                acc = fmaf(cw, g, acc);
            }
        }
    }
    out[bq * DD + h * DH + dh] = acc;
}

// ------------------------------------------------------------------
// LayerNorm over last dim 256; one wave per row
// ------------------------------------------------------------------
__global__ __launch_bounds__(256) void ln_kernel(
    const float* __restrict__ x, const float* __restrict__ g,
    const float* __restrict__ bta, float* __restrict__ out)
{
    int row = blockIdx.x * 4 + (threadIdx.x >> 6);
    int lane = threadIdx.x & 63;
    const float* xp = x + (size_t)row * DD;
    float vals[4];
    float s = 0.f, s2 = 0.f;
#pragma unroll
    for (int j = 0; j < 4; ++j) {
        float vv = xp[j * 64 + lane];
        vals[j] = vv;
        s += vv; s2 += vv * vv;
    }
#pragma unroll
    for (int o = 32; o > 0; o >>= 1) {
        s  += __shfl_xor(s, o);
        s2 += __shfl_xor(s2, o);
    }
    float m = s * (1.f / DD);
    float var = s2 * (1.f / DD) - m * m;
    float r = rsqrtf(var + 1e-5f);
#pragma unroll
    for (int j = 0; j < 4; ++j) {
        int d = j * 64 + lane;
        out[(size_t)row * DD + d] = (vals[j] - m) * r * g[d] + bta[d];
    }
}

// add: o = a + b (float4 granularity)
__global__ __launch_bounds__(256) void add_kernel(
    const float* __restrict__ a, const float* __restrict__ b,
    float* __restrict__ o, int n4)
{
    int i = blockIdx.x * 256 + threadIdx.x;
    if (i < n4) {
        float4 x = ((const float4*)a)[i];
        float4 y = ((const float4*)b)[i];
        ((float4*)o)[i] = make_float4(x.x + y.x, x.y + y.y, x.z + y.z, x.w + y.w);
    }
}

// ------------------------------------------------------------------
extern "C" void kernel_launch(void* const* d_in, const int* in_sizes, int n_in,
                              void* d_out, int out_size, void* d_ws, size_t ws_size,
                              hipStream_t stream)
{
    const float* src[4]  = {(const float*)d_in[0], (const float*)d_in[3],
                            (const float*)d_in[6], (const float*)d_in[9]};
    const float* q_feat  = (const float*)d_in[12];
    const float* q_pos   = (const float*)d_in[13];
    const float* q_ref   = (const float*)d_in[14];
    const float* so_w = (const float*)d_in[16];
    const float* so_b = (const float*)d_in[17];
    const float* aw_w = (const float*)d_in[18];
    const float* aw_b = (const float*)d_in[19];
    const float* vp_w = (const float*)d_in[20];
    const float* vp_b = (const float*)d_in[21];
    const float* op_w = (const float*)d_in[22];
    const float* op_b = (const float*)d_in[23];
    const float* n1_g = (const float*)d_in[24];
    const float* n1_b = (const float*)d_in[25];
    const float* l1_w = (const float*)d_in[26];
    const float* l1_b = (const float*)d_in[27];
    const float* l2_w = (const float*)d_in[28];
    const float* l2_b = (const float*)d_in[29];
    const float* n2_g = (const float*)d_in[30];
    const float* n2_b = (const float*)d_in[31];

    float* ws = (float*)d_ws;
    float* src_flat = ws;                 ws += (size_t)BB * SS * DD;   // 11,141,120
    float* v_buf    = ws;                 ws += (size_t)BB * SS * DD;   // 11,141,120
    float* q_buf    = ws;                 ws += (size_t)BB * NQ * DD;   //  2,097,152
    float* offs     = ws;                 ws += (size_t)BB * NQ * 256;  //  2,097,152
    float* awb      = ws;                 ws += (size_t)BB * NQ * 128;  //  1,048,576
    float* msda     = ws;                 ws += (size_t)BB * NQ * DD;   //  2,097,152
    float* tmp      = ws;                 ws += (size_t)BB * NQ * DD;   //  2,097,152
    float* hbuf     = ws;                 ws += (size_t)BB * NQ * DFF;  //  8,388,608

    float* qf = (float*)d_out;            // residual stream lives in d_out

    // one-time: flatten sources (B,D,H,W) -> (B,S,D)
    {
        int HW[4] = {16384, 4096, 1024, 256};
        int st[4] = {0, 16384, 20480, 21504};
        for (int l = 0; l < 4; ++l) {
            dim3 grid(HW[l] / 64, DD / 64, BB);
            flatten_kernel<<<grid, 256, 0, stream>>>(src[l], src_flat, HW[l], st[l]);
        }
        hipMemcpyAsync(qf, q_feat, (size_t)BB * NQ * DD * sizeof(float),
                       hipMemcpyDeviceToDevice, stream);
    }

    const int RQ = BB * NQ;       // 8192 query rows
    const int RV = BB * SS;       // 43520 value rows

    for (int l = 0; l < NL; ++l) {
        const float* so_wl = so_w + (size_t)l * 256 * 256;
        const float* so_bl = so_b + (size_t)l * 256;
        const float* aw_wl = aw_w + (size_t)l * 128 * 256;
        const float* aw_bl = aw_b + (size_t)l * 128;
        const float* vp_wl = vp_w + (size_t)l * 256 * 256;
        const float* vp_bl = vp_b + (size_t)l * 256;
        const float* op_wl = op_w + (size_t)l * 256 * 256;
        const float* op_bl = op_b + (size_t)l * 256;
        const float* l1_wl = l1_w + (size_t)l * DFF * 256;
        const float* l1_bl = l1_b + (size_t)l * DFF;
        const float* l2_wl = l2_w + (size_t)l * 256 * DFF;
        const float* l2_bl = l2_b + (size_t)l * 256;

        // q = qf + q_pos
        add_kernel<<<RQ * DD / (256 * 4), 256, 0, stream>>>(qf, q_pos, q_buf, RQ * DD / 4);

        // v = src_flat @ vp_w^T + vp_b  -> (B,NH,S,DH) layout
        gemm_nt<256, EPI_VSC><<<dim3(RV / 64, 4), 256, 0, stream>>>(
            src_flat, vp_wl, vp_bl, nullptr, v_buf, 256);

        // sampling offsets and attention weights
        gemm_nt<256, EPI_PLAIN><<<dim3(RQ / 64, 4), 256, 0, stream>>>(
            q_buf, so_wl, so_bl, nullptr, offs, 256);
        gemm_nt<256, EPI_PLAIN><<<dim3(RQ / 64, 2), 256, 0, stream>>>(
            q_buf, aw_wl, aw_bl, nullptr, awb, 128);
        softmax16<<<(RQ * NH) / 256, 256, 0, stream>>>(awb);

        // bilinear sampling + weighted aggregation -> msda (B,NQ,D)
        msda_kernel<<<(BB * NQ * NH) / 8, 256, 0, stream>>>(v_buf, offs, awb, q_ref, msda);

        // output projection + residual -> tmp; LN1 -> qf
        gemm_nt<256, EPI_RES><<<dim3(RQ / 64, 4), 256, 0, stream>>>(
            msda, op_wl, op_bl, qf, tmp, 256);
        ln_kernel<<<RQ / 4, 256, 0, stream>>>(tmp, n1_g + l * 256, n1_b + l * 256, qf);

        // FFN
        gemm_nt<256, EPI_RELU><<<dim3(RQ / 64, DFF / 64), 256, 0, stream>>>(
            qf, l1_wl, l1_bl, nullptr, hbuf, DFF);
        gemm_nt<1024, EPI_RES><<<dim3(RQ / 64, 4), 256, 0, stream>>>(
            hbuf, l2_wl, l2_bl, qf, tmp, 256);
        ln_kernel<<<RQ / 4, 256, 0, stream>>>(tmp, n2_g + l * 256, n2_b + l * 256, qf);
    }

    (void)in_sizes; (void)n_in; (void)out_size; (void)ws_size;
}

// Round 2
// 948.283 us; speedup vs baseline: 2.0360x; 2.0360x over previous
//
#include <hip/hip_runtime.h>
#include <math.h>

// ---- problem constants ----
#define BB 2
#define DD 256
#define NH 8
#define DH 32
#define NPNP 4
#define LV 4
#define NQ 4096
#define NL 6
#define DFF 1024
#define SS 21760   // 128*128 + 64*64 + 32*32 + 16*16

typedef short v8s __attribute__((ext_vector_type(8)));
typedef float v4f __attribute__((ext_vector_type(4)));

__device__ __forceinline__ ushort f2b(float f) {
    union { float f; unsigned u; } v; v.f = f;
    unsigned r = v.u + 0x7fffu + ((v.u >> 16) & 1u);
    return (ushort)(r >> 16);
}
__device__ __forceinline__ float b2f(ushort u) {
    union { unsigned u; float f; } v; v.u = ((unsigned)u) << 16;
    return v.f;
}

__device__ __constant__ int c_dims[4]   = {128, 64, 32, 16};
__device__ __constant__ int c_starts[4] = {0, 16384, 20480, 21504};

// ------------------------------------------------------------------
// flatten: src (B, D, H, W) f32 -> src_flat (B, S, D) bf16
// ------------------------------------------------------------------
__global__ __launch_bounds__(256) void flatten_kernel(
    const float* __restrict__ src, ushort* __restrict__ dst, int HW, int start)
{
    __shared__ float tile[64][65];
    const int b  = blockIdx.z;
    const int d0 = blockIdx.y * 64;
    const int s0 = blockIdx.x * 64;
    const int t  = threadIdx.x;
    const float* sp = src + ((size_t)b * DD + d0) * (size_t)HW + s0;
#pragma unroll
    for (int i = 0; i < 16; ++i) {
        int lin = i * 256 + t;
        int dl = lin >> 6, sl = lin & 63;
        tile[sl][dl] = sp[(size_t)dl * HW + sl];
    }
    __syncthreads();
    ushort* dp = dst + ((size_t)b * SS + start + s0) * DD + d0;
#pragma unroll
    for (int i = 0; i < 16; ++i) {
        int lin = i * 256 + t;
        int sl = lin >> 6, dl = lin & 63;
        dp[(size_t)sl * DD + dl] = f2b(tile[sl][dl]);
    }
}

// f32 -> bf16 convert (n4 = n/4)
__global__ __launch_bounds__(256) void cvt_kernel(
    const float* __restrict__ in, ushort* __restrict__ out, int n4)
{
    int i = blockIdx.x * 256 + threadIdx.x;
    if (i < n4) {
        float4 x = ((const float4*)in)[i];
        uint2 pk;
        pk.x = (unsigned)f2b(x.x) | ((unsigned)f2b(x.y) << 16);
        pk.y = (unsigned)f2b(x.z) | ((unsigned)f2b(x.w) << 16);
        ((uint2*)out)[i] = pk;
    }
}

// q = bf16(qf + q_pos)
__global__ __launch_bounds__(256) void add_bf_kernel(
    const float* __restrict__ a, const float* __restrict__ b,
    ushort* __restrict__ o, int n4)
{
    int i = blockIdx.x * 256 + threadIdx.x;
    if (i < n4) {
        float4 x = ((const float4*)a)[i];
        float4 y = ((const float4*)b)[i];
        uint2 pk;
        pk.x = (unsigned)f2b(x.x + y.x) | ((unsigned)f2b(x.y + y.y) << 16);
        pk.y = (unsigned)f2b(x.z + y.z) | ((unsigned)f2b(x.w + y.w) << 16);
        ((uint2*)o)[i] = pk;
    }
}

// ------------------------------------------------------------------
// bf16 MFMA NT GEMM: out[r,e] = sum_k A[r,k]*W[e,k] + bias[e]
// 128x128 tile, BK=64, 4 waves (2x2), each wave 64x64 via 4x4 16x16x32 frags.
// LDS staged via global_load_lds(16B) with XOR chunk swizzle:
//   LDS(row, cs) holds global chunk c = cs ^ (row&7)  (chunk = 16B)
// ------------------------------------------------------------------
enum { EPI_PLAIN = 0, EPI_RELUB = 1, EPI_RES = 2, EPI_VSC = 3 };

template <int K, int EPI>
__global__ __launch_bounds__(256) void gemm_bf16(
    const ushort* __restrict__ A, const ushort* __restrict__ W,
    const float* __restrict__ bias, const float* __restrict__ res,
    void* __restrict__ out, int E)
{
    __shared__ ushort As[128 * 64];
    __shared__ ushort Ws[128 * 64];
    const int tid  = threadIdx.x;
    const int wave = tid >> 6, lane = tid & 63;
    const size_t r0 = (size_t)blockIdx.x * 128;
    const int e0 = blockIdx.y * 128;
    const int wrow = wave >> 1, wcol = wave & 1;

    v4f acc[4][4];
#pragma unroll
    for (int m = 0; m < 4; ++m)
#pragma unroll
        for (int n = 0; n < 4; ++n)
#pragma unroll
            for (int j = 0; j < 4; ++j) acc[m][n][j] = 0.f;

    // staging: lane -> (row-in-32-group, source chunk)
    const int srow   = lane >> 3;                    // 0..7
    const int schunk = (lane & 7) ^ (srow & 7);      // inverse swizzle on source
    const ushort* Ag = A + (r0 + wave * 8 + srow) * K + schunk * 8;
    const ushort* Wg = W + ((size_t)(e0 + wave * 8 + srow)) * K + schunk * 8;

    for (int k0 = 0; k0 < K; k0 += 64) {
#pragma unroll
        for (int i = 0; i < 4; ++i) {
            __builtin_amdgcn_global_load_lds(
                (const __attribute__((address_space(1))) void*)(Ag + (size_t)(i * 32) * K + k0),
                (__attribute__((address_space(3))) void*)(As + (i * 32 + wave * 8) * 64),
                16, 0, 0);
            __builtin_amdgcn_global_load_lds(
                (const __attribute__((address_space(1))) void*)(Wg + (size_t)(i * 32) * K + k0),
                (__attribute__((address_space(3))) void*)(Ws + (i * 32 + wave * 8) * 64),
                16, 0, 0);
        }
        __syncthreads();

        const int rlo = lane & 15;
#pragma unroll
        for (int ks = 0; ks < 2; ++ks) {
            const int chi = ks * 4 + (lane >> 4);
            v8s af[4], bf[4];
#pragma unroll
            for (int m = 0; m < 4; ++m) {
                int r = wrow * 64 + m * 16 + rlo;
                af[m] = *(const v8s*)((const char*)As + r * 128 + ((chi ^ (r & 7)) << 4));
            }
#pragma unroll
            for (int n = 0; n < 4; ++n) {
                int r = wcol * 64 + n * 16 + rlo;
                bf[n] = *(const v8s*)((const char*)Ws + r * 128 + ((chi ^ (r & 7)) << 4));
            }
#pragma unroll
            for (int m = 0; m < 4; ++m)
#pragma unroll
                for (int n = 0; n < 4; ++n)
                    acc[m][n] = __builtin_amdgcn_mfma_f32_16x16x32_bf16(
                        af[m], bf[n], acc[m][n], 0, 0, 0);
        }
        __syncthreads();
    }

    // epilogue: C/D layout col = lane&15, row = (lane>>4)*4 + j
    const int lrow = (lane >> 4) << 2;
    const int lcol = lane & 15;
#pragma unroll
    for (int m = 0; m < 4; ++m) {
#pragma unroll
        for (int n = 0; n < 4; ++n) {
            const int ecol = e0 + wcol * 64 + n * 16 + lcol;
            const float bv = bias[ecol];
#pragma unroll
            for (int j = 0; j < 4; ++j) {
                const size_t row = r0 + wrow * 64 + m * 16 + lrow + j;
                float val = acc[m][n][j] + bv;
                if (EPI == EPI_RELUB) {
                    ((ushort*)out)[row * E + ecol] = f2b(fmaxf(val, 0.f));
                } else if (EPI == EPI_VSC) {
                    int b = (int)(row / SS), s = (int)(row % SS);
                    ((ushort*)out)[(((size_t)b * NH + (ecol >> 5)) * SS + s) * DH + (ecol & 31)]
                        = f2b(val);
                } else if (EPI == EPI_RES) {
                    ((float*)out)[row * E + ecol] = val + res[row * E + ecol];
                } else {
                    ((float*)out)[row * E + ecol] = val;
                }
            }
        }
    }
}

// ------------------------------------------------------------------
// softmax over rows of 16 (in place)
// ------------------------------------------------------------------
__global__ __launch_bounds__(256) void softmax16(float* __restrict__ aw)
{
    int i = blockIdx.x * 256 + threadIdx.x;
    float* p = aw + (size_t)i * 16;
    float m = -1e30f;
#pragma unroll
    for (int j = 0; j < 16; ++j) m = fmaxf(m, p[j]);
    float s = 0.f;
    float e[16];
#pragma unroll
    for (int j = 0; j < 16; ++j) { e[j] = expf(p[j] - m); s += e[j]; }
    float inv = 1.f / s;
#pragma unroll
    for (int j = 0; j < 16; ++j) p[j] = e[j] * inv;
}

// ------------------------------------------------------------------
// MSDA sampling + aggregation. v is bf16 (B,NH,S,DH); out bf16 (B,NQ,D)
// ------------------------------------------------------------------
__global__ __launch_bounds__(256) void msda_kernel(
    const ushort* __restrict__ v, const float* __restrict__ offs,
    const float* __restrict__ aw, const float* __restrict__ qref,
    ushort* __restrict__ out)
{
    int gid = blockIdx.x * 8 + (threadIdx.x >> 5);
    int dh = threadIdx.x & 31;
    int h = gid & 7;
    int q = (gid >> 3) & (NQ - 1);
    int b = gid >> 15;
    size_t bq = (size_t)b * NQ + q;
    const ushort* vb = v + ((size_t)b * NH + h) * (size_t)SS * DH;
    float rx = qref[bq * 2 + 0];
    float ry = qref[bq * 2 + 1];
    const float* op = offs + (bq * NH + h) * (LV * NPNP * 2);
    const float* ap = aw + (bq * NH + h) * (LV * NPNP);
    float acc = 0.f;
#pragma unroll
    for (int l = 0; l < LV; ++l) {
        const int Wl = c_dims[l];
        const int st = c_starts[l];
        const float fW = (float)Wl;
#pragma unroll
        for (int p = 0; p < NPNP; ++p) {
            float a = ap[l * NPNP + p];
            float x = fmaf(rx, fW, op[(l * NPNP + p) * 2 + 0]) - 0.5f;
            float y = fmaf(ry, fW, op[(l * NPNP + p) * 2 + 1]) - 0.5f;
            float x0f = floorf(x), y0f = floorf(y);
            float wx = x - x0f, wy = y - y0f;
            int x0 = (int)x0f, y0 = (int)y0f;
#pragma unroll
            for (int c = 0; c < 4; ++c) {
                int dx = c & 1, dy = c >> 1;
                int xc = x0 + dx, yc = y0 + dy;
                bool valid = (xc >= 0) & (xc < Wl) & (yc >= 0) & (yc < Wl);
                int xi = min(max(xc, 0), Wl - 1);
                int yi = min(max(yc, 0), Wl - 1);
                float w = (dx ? wx : 1.f - wx) * (dy ? wy : 1.f - wy);
                float g = b2f(vb[((size_t)(st + yi * Wl + xi)) * DH + dh]);
                float cw = valid ? (a * w) : 0.f;
                acc = fmaf(cw, g, acc);
            }
        }
    }
    out[bq * DD + h * DH + dh] = f2b(acc);
}

// ------------------------------------------------------------------
// LayerNorm over last dim 256; one wave per row; optional bf16 copy
// ------------------------------------------------------------------
__global__ __launch_bounds__(256) void ln_kernel(
    const float* __restrict__ x, const float* __restrict__ g,
    const float* __restrict__ bta, float* __restrict__ out,
    ushort* __restrict__ bfout)
{
    int row = blockIdx.x * 4 + (threadIdx.x >> 6);
    int lane = threadIdx.x & 63;
    const float* xp = x + (size_t)row * DD;
    float vals[4];
    float s = 0.f, s2 = 0.f;
#pragma unroll
    for (int j = 0; j < 4; ++j) {
        float vv = xp[j * 64 + lane];
        vals[j] = vv;
        s += vv; s2 += vv * vv;
    }
#pragma unroll
    for (int o = 32; o > 0; o >>= 1) {
        s  += __shfl_xor(s, o);
        s2 += __shfl_xor(s2, o);
    }
    float m = s * (1.f / DD);
    float var = s2 * (1.f / DD) - m * m;
    float r = rsqrtf(var + 1e-5f);
#pragma unroll
    for (int j = 0; j < 4; ++j) {
        int d = j * 64 + lane;
        float val = (vals[j] - m) * r * g[d] + bta[d];
        out[(size_t)row * DD + d] = val;
        if (bfout) bfout[(size_t)row * DD + d] = f2b(val);
    }
}

// ------------------------------------------------------------------
extern "C" void kernel_launch(void* const* d_in, const int* in_sizes, int n_in,
                              void* d_out, int out_size, void* d_ws, size_t ws_size,
                              hipStream_t stream)
{
    const float* src[4]  = {(const float*)d_in[0], (const float*)d_in[3],
                            (const float*)d_in[6], (const float*)d_in[9]};
    const float* q_feat  = (const float*)d_in[12];
    const float* q_pos   = (const float*)d_in[13];
    const float* q_ref   = (const float*)d_in[14];
    const float* so_w = (const float*)d_in[16];
    const float* so_b = (const float*)d_in[17];
    const float* aw_w = (const float*)d_in[18];
    const float* aw_b = (const float*)d_in[19];
    const float* vp_w = (const float*)d_in[20];
    const float* vp_b = (const float*)d_in[21];
    const float* op_w = (const float*)d_in[22];
    const float* op_b = (const float*)d_in[23];
    const float* n1_g = (const float*)d_in[24];
    const float* n1_b = (const float*)d_in[25];
    const float* l1_w = (const float*)d_in[26];
    const float* l1_b = (const float*)d_in[27];
    const float* l2_w = (const float*)d_in[28];
    const float* l2_b = (const float*)d_in[29];
    const float* n2_g = (const float*)d_in[30];
    const float* n2_b = (const float*)d_in[31];

    char* p = (char*)d_ws;
    auto alloc = [&](size_t bytes) { char* r = p; p += (bytes + 255) & ~255ULL; return r; };

    ushort* src_flat = (ushort*)alloc((size_t)BB * SS * DD * 2);
    ushort* v_buf    = (ushort*)alloc((size_t)BB * NH * SS * DH * 2);
    ushort* q_bf     = (ushort*)alloc((size_t)BB * NQ * DD * 2);
    float*  offs     = (float*) alloc((size_t)BB * NQ * 256 * 4);
    float*  awb      = (float*) alloc((size_t)BB * NQ * 128 * 4);
    ushort* msda_bf  = (ushort*)alloc((size_t)BB * NQ * DD * 2);
    float*  tmp      = (float*) alloc((size_t)BB * NQ * DD * 4);
    ushort* hbuf     = (ushort*)alloc((size_t)BB * NQ * DFF * 2);
    ushort* qf_bf    = (ushort*)alloc((size_t)BB * NQ * DD * 2);
    ushort* w_so     = (ushort*)alloc((size_t)NL * 256 * 256 * 2);
    ushort* w_aw     = (ushort*)alloc((size_t)NL * 128 * 256 * 2);
    ushort* w_vp     = (ushort*)alloc((size_t)NL * 256 * 256 * 2);
    ushort* w_op     = (ushort*)alloc((size_t)NL * 256 * 256 * 2);
    ushort* w_l1     = (ushort*)alloc((size_t)NL * DFF * 256 * 2);
    ushort* w_l2     = (ushort*)alloc((size_t)NL * 256 * DFF * 2);

    float* qf = (float*)d_out;   // residual stream lives in d_out

    // weight conversion (per launch; deterministic)
    cvt_kernel<<<(NL * 256 * 256 / 4 + 255) / 256, 256, 0, stream>>>(so_w, w_so, NL * 256 * 256 / 4);
    cvt_kernel<<<(NL * 128 * 256 / 4 + 255) / 256, 256, 0, stream>>>(aw_w, w_aw, NL * 128 * 256 / 4);
    cvt_kernel<<<(NL * 256 * 256 / 4 + 255) / 256, 256, 0, stream>>>(vp_w, w_vp, NL * 256 * 256 / 4);
    cvt_kernel<<<(NL * 256 * 256 / 4 + 255) / 256, 256, 0, stream>>>(op_w, w_op, NL * 256 * 256 / 4);
    cvt_kernel<<<(NL * DFF * 256 / 4 + 255) / 256, 256, 0, stream>>>(l1_w, w_l1, NL * DFF * 256 / 4);
    cvt_kernel<<<(NL * DFF * 256 / 4 + 255) / 256, 256, 0, stream>>>(l2_w, w_l2, NL * DFF * 256 / 4);

    // flatten sources (B,D,H,W) -> (B,S,D) bf16
    {
        int HW[4] = {16384, 4096, 1024, 256};
        int st[4] = {0, 16384, 20480, 21504};
        for (int l = 0; l < 4; ++l) {
            dim3 grid(HW[l] / 64, DD / 64, BB);
            flatten_kernel<<<grid, 256, 0, stream>>>(src[l], src_flat, HW[l], st[l]);
        }
        hipMemcpyAsync(qf, q_feat, (size_t)BB * NQ * DD * sizeof(float),
                       hipMemcpyDeviceToDevice, stream);
    }

    const int RQ = BB * NQ;       // 8192 query rows
    const int RV = BB * SS;       // 43520 value rows

    for (int l = 0; l < NL; ++l) {
        const float* vp_bl = vp_b + (size_t)l * 256;
        const float* so_bl = so_b + (size_t)l * 256;
        const float* aw_bl = aw_b + (size_t)l * 128;
        const float* op_bl = op_b + (size_t)l * 256;
        const float* l1_bl = l1_b + (size_t)l * DFF;
        const float* l2_bl = l2_b + (size_t)l * 256;

        // q = bf16(qf + q_pos)
        add_bf_kernel<<<RQ * DD / (256 * 4), 256, 0, stream>>>(qf, q_pos, q_bf, RQ * DD / 4);

        // v = src_flat @ vp_w^T + vp_b  -> (B,NH,S,DH) bf16
        gemm_bf16<256, EPI_VSC><<<dim3(RV / 128, 2), 256, 0, stream>>>(
            src_flat, w_vp + (size_t)l * 256 * 256, vp_bl, nullptr, v_buf, 256);

        // sampling offsets and attention weights (f32 out)
        gemm_bf16<256, EPI_PLAIN><<<dim3(RQ / 128, 2), 256, 0, stream>>>(
            q_bf, w_so + (size_t)l * 256 * 256, so_bl, nullptr, offs, 256);
        gemm_bf16<256, EPI_PLAIN><<<dim3(RQ / 128, 1), 256, 0, stream>>>(
            q_bf, w_aw + (size_t)l * 128 * 256, aw_bl, nullptr, awb, 128);
        softmax16<<<(RQ * NH) / 256, 256, 0, stream>>>(awb);

        // bilinear sampling + weighted aggregation -> msda_bf (B,NQ,D)
        msda_kernel<<<(BB * NQ * NH) / 8, 256, 0, stream>>>(v_buf, offs, awb, q_ref, msda_bf);

        // output projection + residual -> tmp; LN1 -> qf (+bf16 copy)
        gemm_bf16<256, EPI_RES><<<dim3(RQ / 128, 2), 256, 0, stream>>>(
            msda_bf, w_op + (size_t)l * 256 * 256, op_bl, qf, tmp, 256);
        ln_kernel<<<RQ / 4, 256, 0, stream>>>(tmp, n1_g + l * 256, n1_b + l * 256, qf, qf_bf);

        // FFN
        gemm_bf16<256, EPI_RELUB><<<dim3(RQ / 128, DFF / 128), 256, 0, stream>>>(
            qf_bf, w_l1 + (size_t)l * DFF * 256, l1_bl, nullptr, hbuf, DFF);
        gemm_bf16<1024, EPI_RES><<<dim3(RQ / 128, 2), 256, 0, stream>>>(
            hbuf, w_l2 + (size_t)l * 256 * DFF, l2_bl, qf, tmp, 256);
        ln_kernel<<<RQ / 4, 256, 0, stream>>>(tmp, n2_g + l * 256, n2_b + l * 256, qf, nullptr);
    }

    (void)in_sizes; (void)n_in; (void)out_size; (void)ws_size;
}

// Round 3
// 832.432 us; speedup vs baseline: 2.3194x; 1.1392x over previous
//
#include <hip/hip_runtime.h>
#include <math.h>

// ---- problem constants ----
#define BB 2
#define DD 256
#define NH 8
#define DH 32
#define NPNP 4
#define LV 4
#define NQ 4096
#define NL 6
#define DFF 1024
#define SS 21760   // 128*128 + 64*64 + 32*32 + 16*16

typedef short v8s __attribute__((ext_vector_type(8)));
typedef float v4f __attribute__((ext_vector_type(4)));

__device__ __forceinline__ ushort f2b(float f) {
    union { float f; unsigned u; } v; v.f = f;
    unsigned r = v.u + 0x7fffu + ((v.u >> 16) & 1u);
    return (ushort)(r >> 16);
}

__device__ __constant__ int c_dims[4]   = {128, 64, 32, 16};
__device__ __constant__ int c_starts[4] = {0, 16384, 20480, 21504};

// ------------------------------------------------------------------
// flatten: src (B, D, H, W) f32 -> src_flat (B, S, D) bf16
// ------------------------------------------------------------------
__global__ __launch_bounds__(256) void flatten_kernel(
    const float* __restrict__ src, ushort* __restrict__ dst, int HW, int start)
{
    __shared__ float tile[64][65];
    const int b  = blockIdx.z;
    const int d0 = blockIdx.y * 64;
    const int s0 = blockIdx.x * 64;
    const int t  = threadIdx.x;
    const float* sp = src + ((size_t)b * DD + d0) * (size_t)HW + s0;
#pragma unroll
    for (int i = 0; i < 16; ++i) {
        int lin = i * 256 + t;
        int dl = lin >> 6, sl = lin & 63;
        tile[sl][dl] = sp[(size_t)dl * HW + sl];
    }
    __syncthreads();
    ushort* dp = dst + ((size_t)b * SS + start + s0) * DD + d0;
#pragma unroll
    for (int i = 0; i < 16; ++i) {
        int lin = i * 256 + t;
        int sl = lin >> 6, dl = lin & 63;
        dp[(size_t)sl * DD + dl] = f2b(tile[sl][dl]);
    }
}

// f32 -> bf16 convert (n4 = n/4)
__global__ __launch_bounds__(256) void cvt_kernel(
    const float* __restrict__ in, ushort* __restrict__ out, int n4)
{
    int i = blockIdx.x * 256 + threadIdx.x;
    if (i < n4) {
        float4 x = ((const float4*)in)[i];
        uint2 pk;
        pk.x = (unsigned)f2b(x.x) | ((unsigned)f2b(x.y) << 16);
        pk.y = (unsigned)f2b(x.z) | ((unsigned)f2b(x.w) << 16);
        ((uint2*)out)[i] = pk;
    }
}

// q = bf16(qf + q_pos)
__global__ __launch_bounds__(256) void add_bf_kernel(
    const float* __restrict__ a, const float* __restrict__ b,
    ushort* __restrict__ o, int n4)
{
    int i = blockIdx.x * 256 + threadIdx.x;
    if (i < n4) {
        float4 x = ((const float4*)a)[i];
        float4 y = ((const float4*)b)[i];
        uint2 pk;
        pk.x = (unsigned)f2b(x.x + y.x) | ((unsigned)f2b(x.y + y.y) << 16);
        pk.y = (unsigned)f2b(x.z + y.z) | ((unsigned)f2b(x.w + y.w) << 16);
        ((uint2*)o)[i] = pk;
    }
}

// ------------------------------------------------------------------
// bf16 MFMA NT GEMM: out[r,e] = sum_k A[r,k]*W[e,k] + bias[e]
// 128x128 tile, BK=64, 4 waves (2x2), each wave 64x64 via 4x4 16x16x32 frags.
// LDS staged via global_load_lds(16B) with XOR chunk swizzle.
// ------------------------------------------------------------------
enum { EPI_PLAIN = 0, EPI_RELUB = 1, EPI_RES = 2, EPI_VSC = 3 };

template <int K, int EPI>
__global__ __launch_bounds__(256) void gemm_bf16(
    const ushort* __restrict__ A, const ushort* __restrict__ W,
    const float* __restrict__ bias, const float* __restrict__ res,
    void* __restrict__ out, int E)
{
    __shared__ ushort As[128 * 64];
    __shared__ ushort Ws[128 * 64];
    const int tid  = threadIdx.x;
    const int wave = tid >> 6, lane = tid & 63;
    const size_t r0 = (size_t)blockIdx.x * 128;
    const int e0 = blockIdx.y * 128;
    const int wrow = wave >> 1, wcol = wave & 1;

    v4f acc[4][4];
#pragma unroll
    for (int m = 0; m < 4; ++m)
#pragma unroll
        for (int n = 0; n < 4; ++n)
#pragma unroll
            for (int j = 0; j < 4; ++j) acc[m][n][j] = 0.f;

    const int srow   = lane >> 3;                    // 0..7
    const int schunk = (lane & 7) ^ (srow & 7);      // inverse swizzle on source
    const ushort* Ag = A + (r0 + wave * 8 + srow) * K + schunk * 8;
    const ushort* Wg = W + ((size_t)(e0 + wave * 8 + srow)) * K + schunk * 8;

    for (int k0 = 0; k0 < K; k0 += 64) {
#pragma unroll
        for (int i = 0; i < 4; ++i) {
            __builtin_amdgcn_global_load_lds(
                (const __attribute__((address_space(1))) void*)(Ag + (size_t)(i * 32) * K + k0),
                (__attribute__((address_space(3))) void*)(As + (i * 32 + wave * 8) * 64),
                16, 0, 0);
            __builtin_amdgcn_global_load_lds(
                (const __attribute__((address_space(1))) void*)(Wg + (size_t)(i * 32) * K + k0),
                (__attribute__((address_space(3))) void*)(Ws + (i * 32 + wave * 8) * 64),
                16, 0, 0);
        }
        __syncthreads();

        const int rlo = lane & 15;
#pragma unroll
        for (int ks = 0; ks < 2; ++ks) {
            const int chi = ks * 4 + (lane >> 4);
            v8s af[4], bf[4];
#pragma unroll
            for (int m = 0; m < 4; ++m) {
                int r = wrow * 64 + m * 16 + rlo;
                af[m] = *(const v8s*)((const char*)As + r * 128 + ((chi ^ (r & 7)) << 4));
            }
#pragma unroll
            for (int n = 0; n < 4; ++n) {
                int r = wcol * 64 + n * 16 + rlo;
                bf[n] = *(const v8s*)((const char*)Ws + r * 128 + ((chi ^ (r & 7)) << 4));
            }
#pragma unroll
            for (int m = 0; m < 4; ++m)
#pragma unroll
                for (int n = 0; n < 4; ++n)
                    acc[m][n] = __builtin_amdgcn_mfma_f32_16x16x32_bf16(
                        af[m], bf[n], acc[m][n], 0, 0, 0);
        }
        __syncthreads();
    }

    // epilogue: C/D layout col = lane&15, row = (lane>>4)*4 + j
    const int lrow = (lane >> 4) << 2;
    const int lcol = lane & 15;
#pragma unroll
    for (int m = 0; m < 4; ++m) {
#pragma unroll
        for (int n = 0; n < 4; ++n) {
            const int ecol = e0 + wcol * 64 + n * 16 + lcol;
            const float bv = bias[ecol];
#pragma unroll
            for (int j = 0; j < 4; ++j) {
                const size_t row = r0 + wrow * 64 + m * 16 + lrow + j;
                float val = acc[m][n][j] + bv;
                if (EPI == EPI_RELUB) {
                    ((ushort*)out)[row * E + ecol] = f2b(fmaxf(val, 0.f));
                } else if (EPI == EPI_VSC) {
                    int b = (int)(row / SS), s = (int)(row % SS);
                    ((ushort*)out)[(((size_t)b * NH + (ecol >> 5)) * SS + s) * DH + (ecol & 31)]
                        = f2b(val);
                } else if (EPI == EPI_RES) {
                    ((float*)out)[row * E + ecol] = val + res[row * E + ecol];
                } else {
                    ((float*)out)[row * E + ecol] = val;
                }
            }
        }
    }
}

// ------------------------------------------------------------------
// MSDA sampling + aggregation, wave64 per (b,q,h).
// Phase A (lanes 0..15, one per sampling point): fused softmax over the 16
//   attention logits + bilinear corner indices/weights -> LDS (idx_bytes, w).
// Phase B (all lanes): corner = lane>>4, dh-pair = lane&15; one dword gather
//   per point covers 4 corners x 32 dh in bf16.
// Phase C: shfl reduce over corners; lanes 0..15 write packed bf16.
// v: bf16 (B,NH,S,DH); aw_raw: pre-softmax logits f32 (B,NQ,NH,16)
// ------------------------------------------------------------------
__global__ __launch_bounds__(256) void msda_kernel(
    const ushort* __restrict__ v, const float* __restrict__ offs,
    const float* __restrict__ aw_raw, const float* __restrict__ qref,
    ushort* __restrict__ out)
{
    __shared__ uint2 iw[4][16][4];
    const int wid  = threadIdx.x >> 6;
    const int lane = threadIdx.x & 63;
    const int gid  = blockIdx.x * 4 + wid;
    const int h = gid & 7;
    const int q = (gid >> 3) & (NQ - 1);
    const int b = gid >> 15;
    const size_t bq = (size_t)b * NQ + q;
    const ushort* vb = v + ((size_t)b * NH + h) * (size_t)SS * DH;

    if (lane < 16) {
        const int l = lane >> 2;
        const float* op = offs + bq * 256 + h * 32;
        const float* ap = aw_raw + bq * 128 + h * 16;
        const float rx = qref[bq * 2 + 0];
        const float ry = qref[bq * 2 + 1];
        // fused softmax over 16 points (4-step shfl tree within 16 lanes)
        float a_raw = ap[lane];
        float mx = a_raw;
        mx = fmaxf(mx, __shfl_xor(mx, 1));
        mx = fmaxf(mx, __shfl_xor(mx, 2));
        mx = fmaxf(mx, __shfl_xor(mx, 4));
        mx = fmaxf(mx, __shfl_xor(mx, 8));
        float e = expf(a_raw - mx);
        float sum = e;
        sum += __shfl_xor(sum, 1);
        sum += __shfl_xor(sum, 2);
        sum += __shfl_xor(sum, 4);
        sum += __shfl_xor(sum, 8);
        const float a = e / sum;

        const int Wl = c_dims[l];
        const int st = c_starts[l];
        const float fW = (float)Wl;
        float x = fmaf(rx, fW, op[2 * lane + 0]) - 0.5f;
        float y = fmaf(ry, fW, op[2 * lane + 1]) - 0.5f;
        float x0f = floorf(x), y0f = floorf(y);
        float wx = x - x0f, wy = y - y0f;
        int x0 = (int)x0f, y0 = (int)y0f;
#pragma unroll
        for (int c = 0; c < 4; ++c) {
            int dx = c & 1, dy = c >> 1;
            int xc = x0 + dx, yc = y0 + dy;
            bool valid = (xc >= 0) & (xc < Wl) & (yc >= 0) & (yc < Wl);
            int xi = min(max(xc, 0), Wl - 1);
            int yi = min(max(yc, 0), Wl - 1);
            float w = (dx ? wx : 1.f - wx) * (dy ? wy : 1.f - wy);
            uint2 t;
            t.x = (unsigned)((st + yi * Wl + xi) * (DH * 2));  // byte offset
            t.y = __float_as_uint(valid ? a * w : 0.f);
            iw[wid][lane][c] = t;
        }
    }
    __syncthreads();

    const int c   = lane >> 4;
    const int dh2 = lane & 15;
    float acc0 = 0.f, acc1 = 0.f;
    const char* vbase = (const char*)vb + dh2 * 4;
#pragma unroll
    for (int p = 0; p < 16; ++p) {
        uint2 t = iw[wid][p][c];
        float cw = __uint_as_float(t.y);
        unsigned v2 = *(const unsigned*)(vbase + t.x);
        float lo = __uint_as_float(v2 << 16);
        float hi = __uint_as_float(v2 & 0xffff0000u);
        acc0 = fmaf(cw, lo, acc0);
        acc1 = fmaf(cw, hi, acc1);
    }
    acc0 += __shfl_xor(acc0, 16); acc0 += __shfl_xor(acc0, 32);
    acc1 += __shfl_xor(acc1, 16); acc1 += __shfl_xor(acc1, 32);
    if (lane < 16) {
        unsigned pk = (unsigned)f2b(acc0) | ((unsigned)f2b(acc1) << 16);
        *(unsigned*)(out + bq * DD + h * DH + dh2 * 2) = pk;
    }
}

// ------------------------------------------------------------------
// LayerNorm over last dim 256; one wave per row.
// bfout (optional): bf16 copy of the LN output, with optional q_pos added
// (feeds next layer's q projections).
// ------------------------------------------------------------------
__global__ __launch_bounds__(256) void ln_kernel(
    const float* __restrict__ x, const float* __restrict__ g,
    const float* __restrict__ bta, float* __restrict__ out,
    ushort* __restrict__ bfout, const float* __restrict__ pos)
{
    int row = blockIdx.x * 4 + (threadIdx.x >> 6);
    int lane = threadIdx.x & 63;
    const float* xp = x + (size_t)row * DD;
    float vals[4];
    float s = 0.f, s2 = 0.f;
#pragma unroll
    for (int j = 0; j < 4; ++j) {
        float vv = xp[j * 64 + lane];
        vals[j] = vv;
        s += vv; s2 += vv * vv;
    }
#pragma unroll
    for (int o = 32; o > 0; o >>= 1) {
        s  += __shfl_xor(s, o);
        s2 += __shfl_xor(s2, o);
    }
    float m = s * (1.f / DD);
    float var = s2 * (1.f / DD) - m * m;
    float r = rsqrtf(var + 1e-5f);
#pragma unroll
    for (int j = 0; j < 4; ++j) {
        int d = j * 64 + lane;
        float val = (vals[j] - m) * r * g[d] + bta[d];
        out[(size_t)row * DD + d] = val;
        if (bfout) {
            float bv = pos ? val + pos[(size_t)row * DD + d] : val;
            bfout[(size_t)row * DD + d] = f2b(bv);
        }
    }
}

// ------------------------------------------------------------------
extern "C" void kernel_launch(void* const* d_in, const int* in_sizes, int n_in,
                              void* d_out, int out_size, void* d_ws, size_t ws_size,
                              hipStream_t stream)
{
    const float* src[4]  = {(const float*)d_in[0], (const float*)d_in[3],
                            (const float*)d_in[6], (const float*)d_in[9]};
    const float* q_feat  = (const float*)d_in[12];
    const float* q_pos   = (const float*)d_in[13];
    const float* q_ref   = (const float*)d_in[14];
    const float* so_w = (const float*)d_in[16];
    const float* so_b = (const float*)d_in[17];
    const float* aw_w = (const float*)d_in[18];
    const float* aw_b = (const float*)d_in[19];
    const float* vp_w = (const float*)d_in[20];
    const float* vp_b = (const float*)d_in[21];
    const float* op_w = (const float*)d_in[22];
    const float* op_b = (const float*)d_in[23];
    const float* n1_g = (const float*)d_in[24];
    const float* n1_b = (const float*)d_in[25];
    const float* l1_w = (const float*)d_in[26];
    const float* l1_b = (const float*)d_in[27];
    const float* l2_w = (const float*)d_in[28];
    const float* l2_b = (const float*)d_in[29];
    const float* n2_g = (const float*)d_in[30];
    const float* n2_b = (const float*)d_in[31];

    char* p = (char*)d_ws;
    auto alloc = [&](size_t bytes) { char* r = p; p += (bytes + 255) & ~255ULL; return r; };

    ushort* src_flat = (ushort*)alloc((size_t)BB * SS * DD * 2);
    ushort* v_buf    = (ushort*)alloc((size_t)BB * NH * SS * DH * 2);
    ushort* q_bf     = (ushort*)alloc((size_t)BB * NQ * DD * 2);
    float*  offs     = (float*) alloc((size_t)BB * NQ * 256 * 4);
    float*  awb      = (float*) alloc((size_t)BB * NQ * 128 * 4);
    ushort* msda_bf  = (ushort*)alloc((size_t)BB * NQ * DD * 2);
    float*  tmp      = (float*) alloc((size_t)BB * NQ * DD * 4);
    ushort* hbuf     = (ushort*)alloc((size_t)BB * NQ * DFF * 2);
    ushort* qf_bf    = (ushort*)alloc((size_t)BB * NQ * DD * 2);
    ushort* w_so     = (ushort*)alloc((size_t)NL * 256 * 256 * 2);
    ushort* w_aw     = (ushort*)alloc((size_t)NL * 128 * 256 * 2);
    ushort* w_vp     = (ushort*)alloc((size_t)NL * 256 * 256 * 2);
    ushort* w_op     = (ushort*)alloc((size_t)NL * 256 * 256 * 2);
    ushort* w_l1     = (ushort*)alloc((size_t)NL * DFF * 256 * 2);
    ushort* w_l2     = (ushort*)alloc((size_t)NL * 256 * DFF * 2);

    float* qf = (float*)d_out;   // residual stream lives in d_out

    // weight conversion (per launch; deterministic)
    cvt_kernel<<<(NL * 256 * 256 / 4 + 255) / 256, 256, 0, stream>>>(so_w, w_so, NL * 256 * 256 / 4);
    cvt_kernel<<<(NL * 128 * 256 / 4 + 255) / 256, 256, 0, stream>>>(aw_w, w_aw, NL * 128 * 256 / 4);
    cvt_kernel<<<(NL * 256 * 256 / 4 + 255) / 256, 256, 0, stream>>>(vp_w, w_vp, NL * 256 * 256 / 4);
    cvt_kernel<<<(NL * 256 * 256 / 4 + 255) / 256, 256, 0, stream>>>(op_w, w_op, NL * 256 * 256 / 4);
    cvt_kernel<<<(NL * DFF * 256 / 4 + 255) / 256, 256, 0, stream>>>(l1_w, w_l1, NL * DFF * 256 / 4);
    cvt_kernel<<<(NL * DFF * 256 / 4 + 255) / 256, 256, 0, stream>>>(l2_w, w_l2, NL * DFF * 256 / 4);

    // flatten sources (B,D,H,W) -> (B,S,D) bf16
    {
        int HW[4] = {16384, 4096, 1024, 256};
        int st[4] = {0, 16384, 20480, 21504};
        for (int l = 0; l < 4; ++l) {
            dim3 grid(HW[l] / 64, DD / 64, BB);
            flatten_kernel<<<grid, 256, 0, stream>>>(src[l], src_flat, HW[l], st[l]);
        }
        hipMemcpyAsync(qf, q_feat, (size_t)BB * NQ * DD * sizeof(float),
                       hipMemcpyDeviceToDevice, stream);
    }

    const int RQ = BB * NQ;       // 8192 query rows
    const int RV = BB * SS;       // 43520 value rows

    // q_bf for layer 0: bf16(q_feat + q_pos)
    add_bf_kernel<<<RQ * DD / (256 * 4), 256, 0, stream>>>(q_feat, q_pos, q_bf, RQ * DD / 4);

    for (int l = 0; l < NL; ++l) {
        const float* vp_bl = vp_b + (size_t)l * 256;
        const float* so_bl = so_b + (size_t)l * 256;
        const float* aw_bl = aw_b + (size_t)l * 128;
        const float* op_bl = op_b + (size_t)l * 256;
        const float* l1_bl = l1_b + (size_t)l * DFF;
        const float* l2_bl = l2_b + (size_t)l * 256;

        // v = src_flat @ vp_w^T + vp_b  -> (B,NH,S,DH) bf16
        gemm_bf16<256, EPI_VSC><<<dim3(RV / 128, 2), 256, 0, stream>>>(
            src_flat, w_vp + (size_t)l * 256 * 256, vp_bl, nullptr, v_buf, 256);

        // sampling offsets and attention logits (f32 out; softmax fused in msda)
        gemm_bf16<256, EPI_PLAIN><<<dim3(RQ / 128, 2), 256, 0, stream>>>(
            q_bf, w_so + (size_t)l * 256 * 256, so_bl, nullptr, offs, 256);
        gemm_bf16<256, EPI_PLAIN><<<dim3(RQ / 128, 1), 256, 0, stream>>>(
            q_bf, w_aw + (size_t)l * 128 * 256, aw_bl, nullptr, awb, 128);

        // bilinear sampling + weighted aggregation -> msda_bf (B,NQ,D)
        msda_kernel<<<(BB * NQ * NH) / 4, 256, 0, stream>>>(v_buf, offs, awb, q_ref, msda_bf);

        // output projection + residual -> tmp; LN1 -> qf (+bf16 for FFN)
        gemm_bf16<256, EPI_RES><<<dim3(RQ / 128, 2), 256, 0, stream>>>(
            msda_bf, w_op + (size_t)l * 256 * 256, op_bl, qf, tmp, 256);
        ln_kernel<<<RQ / 4, 256, 0, stream>>>(tmp, n1_g + l * 256, n1_b + l * 256,
                                              qf, qf_bf, nullptr);

        // FFN
        gemm_bf16<256, EPI_RELUB><<<dim3(RQ / 128, DFF / 128), 256, 0, stream>>>(
            qf_bf, w_l1 + (size_t)l * DFF * 256, l1_bl, nullptr, hbuf, DFF);
        gemm_bf16<1024, EPI_RES><<<dim3(RQ / 128, 2), 256, 0, stream>>>(
            hbuf, w_l2 + (size_t)l * 256 * DFF, l2_bl, qf, tmp, 256);
        // LN2 -> qf; bf16(out + q_pos) -> q_bf for next layer's projections
        ln_kernel<<<RQ / 4, 256, 0, stream>>>(tmp, n2_g + l * 256, n2_b + l * 256,
                                              qf, q_bf, q_pos);
    }

    (void)in_sizes; (void)n_in; (void)out_size; (void)ws_size;
}

// Round 7
// 676.674 us; speedup vs baseline: 2.8532x; 1.2302x over previous
//
#include <hip/hip_runtime.h>
#include <math.h>

// ---- problem constants ----
#define BB 2
#define DD 256
#define NH 8
#define DH 32
#define NPNP 4
#define LV 4
#define NQ 4096
#define NL 6
#define DFF 1024
#define SS 21760   // 128*128 + 64*64 + 32*32 + 16*16

typedef short v8s __attribute__((ext_vector_type(8)));
typedef float v4f __attribute__((ext_vector_type(4)));

__device__ __forceinline__ ushort f2b(float f) {
    union { float f; unsigned u; } v; v.f = f;
    unsigned r = v.u + 0x7fffu + ((v.u >> 16) & 1u);
    return (ushort)(r >> 16);
}

__device__ __constant__ int c_dims[4]   = {128, 64, 32, 16};
__device__ __constant__ int c_starts[4] = {0, 16384, 20480, 21504};

// ------------------------------------------------------------------
// flatten: src (B, D, H, W) f32 -> src_flat (B, S, D) bf16
// ------------------------------------------------------------------
__global__ __launch_bounds__(256) void flatten_kernel(
    const float* __restrict__ src, ushort* __restrict__ dst, int HW, int start)
{
    __shared__ float tile[64][65];
    const int b  = blockIdx.z;
    const int d0 = blockIdx.y * 64;
    const int s0 = blockIdx.x * 64;
    const int t  = threadIdx.x;
    const float* sp = src + ((size_t)b * DD + d0) * (size_t)HW + s0;
#pragma unroll
    for (int i = 0; i < 16; ++i) {
        int lin = i * 256 + t;
        int dl = lin >> 6, sl = lin & 63;
        tile[sl][dl] = sp[(size_t)dl * HW + sl];
    }
    __syncthreads();
    ushort* dp = dst + ((size_t)b * SS + start + s0) * DD + d0;
#pragma unroll
    for (int i = 0; i < 16; ++i) {
        int lin = i * 256 + t;
        int sl = lin >> 6, dl = lin & 63;
        dp[(size_t)sl * DD + dl] = f2b(tile[sl][dl]);
    }
}

// f32 -> bf16 convert (n4 = n/4)
__global__ __launch_bounds__(256) void cvt_kernel(
    const float* __restrict__ in, ushort* __restrict__ out, int n4)
{
    int i = blockIdx.x * 256 + threadIdx.x;
    if (i < n4) {
        float4 x = ((const float4*)in)[i];
        uint2 pk;
        pk.x = (unsigned)f2b(x.x) | ((unsigned)f2b(x.y) << 16);
        pk.y = (unsigned)f2b(x.z) | ((unsigned)f2b(x.w) << 16);
        ((uint2*)out)[i] = pk;
    }
}

// q = bf16(qf + q_pos)
__global__ __launch_bounds__(256) void add_bf_kernel(
    const float* __restrict__ a, const float* __restrict__ b,
    ushort* __restrict__ o, int n4)
{
    int i = blockIdx.x * 256 + threadIdx.x;
    if (i < n4) {
        float4 x = ((const float4*)a)[i];
        float4 y = ((const float4*)b)[i];
        uint2 pk;
        pk.x = (unsigned)f2b(x.x + y.x) | ((unsigned)f2b(x.y + y.y) << 16);
        pk.y = (unsigned)f2b(x.z + y.z) | ((unsigned)f2b(x.w + y.w) << 16);
        ((uint2*)o)[i] = pk;
    }
}

// ------------------------------------------------------------------
// bf16 MFMA NT GEMM: out[r,e] = sum_k A[r,k]*W[e,k] + bias[e]
// 128x128 tile, BK=64, 4 waves (2x2), each wave 64x64 via 4x4 16x16x32 frags.
// LDS staged via global_load_lds(16B) with XOR chunk swizzle.
// EPI_QF: E=384 fused q-proj; tile y<2 -> W/bias, write offs f32 (stride 256);
//         tile y==2 -> W2/bias2 (rows-256), write awb f32 (stride 128).
// ------------------------------------------------------------------
enum { EPI_PLAIN = 0, EPI_RELUB = 1, EPI_RES = 2, EPI_VSC = 3, EPI_QF = 4 };

template <int K, int EPI>
__global__ __launch_bounds__(256) void gemm_bf16(
    const ushort* __restrict__ A, const ushort* __restrict__ W,
    const float* __restrict__ bias, const float* __restrict__ res,
    void* __restrict__ out, int E,
    const ushort* __restrict__ W2, const float* __restrict__ bias2,
    void* __restrict__ out2)
{
    __shared__ ushort As[128 * 64];
    __shared__ ushort Ws[128 * 64];
    const int tid  = threadIdx.x;
    const int wave = tid >> 6, lane = tid & 63;
    const size_t r0 = (size_t)blockIdx.x * 128;
    const int e0 = blockIdx.y * 128;
    const int wrow = wave >> 1, wcol = wave & 1;

    const ushort* Wbase = W;
    const float*  bbase = bias;
    int eoff = 0;
    if (EPI == EPI_QF && blockIdx.y == 2) {
        Wbase = W2; bbase = bias2; eoff = 256;
    }

    v4f acc[4][4];
#pragma unroll
    for (int m = 0; m < 4; ++m)
#pragma unroll
        for (int n = 0; n < 4; ++n)
#pragma unroll
            for (int j = 0; j < 4; ++j) acc[m][n][j] = 0.f;

    const int srow   = lane >> 3;                    // 0..7
    const int schunk = (lane & 7) ^ (srow & 7);      // inverse swizzle on source
    const ushort* Ag = A + (r0 + wave * 8 + srow) * K + schunk * 8;
    const ushort* Wg = Wbase + ((size_t)(e0 - eoff + wave * 8 + srow)) * K + schunk * 8;

    for (int k0 = 0; k0 < K; k0 += 64) {
#pragma unroll
        for (int i = 0; i < 4; ++i) {
            __builtin_amdgcn_global_load_lds(
                (const __attribute__((address_space(1))) void*)(Ag + (size_t)(i * 32) * K + k0),
                (__attribute__((address_space(3))) void*)(As + (i * 32 + wave * 8) * 64),
                16, 0, 0);
            __builtin_amdgcn_global_load_lds(
                (const __attribute__((address_space(1))) void*)(Wg + (size_t)(i * 32) * K + k0),
                (__attribute__((address_space(3))) void*)(Ws + (i * 32 + wave * 8) * 64),
                16, 0, 0);
        }
        __syncthreads();

        const int rlo = lane & 15;
#pragma unroll
        for (int ks = 0; ks < 2; ++ks) {
            const int chi = ks * 4 + (lane >> 4);
            v8s af[4], bf[4];
#pragma unroll
            for (int m = 0; m < 4; ++m) {
                int r = wrow * 64 + m * 16 + rlo;
                af[m] = *(const v8s*)((const char*)As + r * 128 + ((chi ^ (r & 7)) << 4));
            }
#pragma unroll
            for (int n = 0; n < 4; ++n) {
                int r = wcol * 64 + n * 16 + rlo;
                bf[n] = *(const v8s*)((const char*)Ws + r * 128 + ((chi ^ (r & 7)) << 4));
            }
#pragma unroll
            for (int m = 0; m < 4; ++m)
#pragma unroll
                for (int n = 0; n < 4; ++n)
                    acc[m][n] = __builtin_amdgcn_mfma_f32_16x16x32_bf16(
                        af[m], bf[n], acc[m][n], 0, 0, 0);
        }
        __syncthreads();
    }

    // epilogue: C/D layout col = lane&15, row = (lane>>4)*4 + j
    const int lrow = (lane >> 4) << 2;
    const int lcol = lane & 15;
#pragma unroll
    for (int m = 0; m < 4; ++m) {
#pragma unroll
        for (int n = 0; n < 4; ++n) {
            const int ecol = e0 + wcol * 64 + n * 16 + lcol;
            const float bv = bbase[ecol - eoff];
#pragma unroll
            for (int j = 0; j < 4; ++j) {
                const size_t row = r0 + wrow * 64 + m * 16 + lrow + j;
                float val = acc[m][n][j] + bv;
                if (EPI == EPI_RELUB) {
                    ((ushort*)out)[row * E + ecol] = f2b(fmaxf(val, 0.f));
                } else if (EPI == EPI_VSC) {
                    int b = (int)(row / SS), s = (int)(row % SS);
                    ((ushort*)out)[(((size_t)b * NH + (ecol >> 5)) * SS + s) * DH + (ecol & 31)]
                        = f2b(val);
                } else if (EPI == EPI_RES) {
                    ((float*)out)[row * E + ecol] = val + res[row * E + ecol];
                } else if (EPI == EPI_QF) {
                    if (eoff == 0) ((float*)out)[row * 256 + ecol] = val;
                    else           ((float*)out2)[row * 128 + (ecol - 256)] = val;
                } else {
                    ((float*)out)[row * E + ecol] = val;
                }
            }
        }
    }
}

// ------------------------------------------------------------------
// MSDA sampling + aggregation, wave64 per (b,q) covering all 8 heads.
// Phase A (2 full-width iters over 128 (h,point) tasks): fused softmax per
//   16-lane group + bilinear corner indices/weights -> LDS (idx_bytes, w).
// Phase B (per head): corner = lane>>4, dh-pair = lane&15; 16 dword gathers.
// Phase C (per head): shfl over corner bits; lanes 0..15 write packed bf16.
// v: bf16 (B,NH,S,DH); awb: pre-softmax logits f32 (B,NQ,NH,16)
// ------------------------------------------------------------------
__global__ __launch_bounds__(256) void msda_kernel(
    const ushort* __restrict__ v, const float* __restrict__ offs,
    const float* __restrict__ awb, const float* __restrict__ qref,
    ushort* __restrict__ out)
{
    __shared__ uint2 iw[4][128][4];
    const int wid  = threadIdx.x >> 6;
    const int lane = threadIdx.x & 63;
    const int gid  = blockIdx.x * 4 + wid;     // (b,q)
    const int q = gid & (NQ - 1);
    const int b = gid >> 12;
    const size_t bq = (size_t)b * NQ + q;

    const float rx = qref[bq * 2 + 0];
    const float ry = qref[bq * 2 + 1];

#pragma unroll
    for (int it = 0; it < 2; ++it) {
        const int t = it * 64 + lane;          // task: h = t>>4, p = t&15
        const int pp = t & 15;
        const int lvl = pp >> 2;
        // softmax over this head's 16 logits (16-lane group)
        float a_raw = awb[bq * 128 + t];
        float mx = a_raw;
        mx = fmaxf(mx, __shfl_xor(mx, 1));
        mx = fmaxf(mx, __shfl_xor(mx, 2));
        mx = fmaxf(mx, __shfl_xor(mx, 4));
        mx = fmaxf(mx, __shfl_xor(mx, 8));
        float e = expf(a_raw - mx);
        float sum = e;
        sum += __shfl_xor(sum, 1);
        sum += __shfl_xor(sum, 2);
        sum += __shfl_xor(sum, 4);
        sum += __shfl_xor(sum, 8);
        const float a = e / sum;

        float2 oxy = *(const float2*)(offs + bq * 256 + t * 2);
        const int Wl = c_dims[lvl];
        const int st = c_starts[lvl];
        const float fW = (float)Wl;
        float x = fmaf(rx, fW, oxy.x) - 0.5f;
        float y = fmaf(ry, fW, oxy.y) - 0.5f;
        float x0f = floorf(x), y0f = floorf(y);
        float wx = x - x0f, wy = y - y0f;
        int x0 = (int)x0f, y0 = (int)y0f;
        const int hbase = (t >> 4) * SS;
#pragma unroll
        for (int c = 0; c < 4; ++c) {
            int dx = c & 1, dy = c >> 1;
            int xc = x0 + dx, yc = y0 + dy;
            bool valid = (xc >= 0) & (xc < Wl) & (yc >= 0) & (yc < Wl);
            int xi = min(max(xc, 0), Wl - 1);
            int yi = min(max(yc, 0), Wl - 1);
            float w = (dx ? wx : 1.f - wx) * (dy ? wy : 1.f - wy);
            uint2 tt;
            tt.x = (unsigned)((hbase + st + yi * Wl + xi) * (DH * 2));  // byte off
            tt.y = __float_as_uint(valid ? a * w : 0.f);
            iw[wid][t][c] = tt;
        }
    }
    __syncthreads();

    const int c   = lane >> 4;
    const int dh2 = lane & 15;
    const char* vbase = (const char*)(v + (size_t)b * NH * SS * DH) + dh2 * 4;
#pragma unroll
    for (int h = 0; h < NH; ++h) {
        float acc0 = 0.f, acc1 = 0.f;
#pragma unroll
        for (int p = 0; p < 16; ++p) {
            uint2 t = iw[wid][h * 16 + p][c];
            float cw = __uint_as_float(t.y);
            unsigned v2 = *(const unsigned*)(vbase + t.x);
            float lo = __uint_as_float(v2 << 16);
            float hi = __uint_as_float(v2 & 0xffff0000u);
            acc0 = fmaf(cw, lo, acc0);
            acc1 = fmaf(cw, hi, acc1);
        }
        acc0 += __shfl_xor(acc0, 16); acc0 += __shfl_xor(acc0, 32);
        acc1 += __shfl_xor(acc1, 16); acc1 += __shfl_xor(acc1, 32);
        if (lane < 16) {
            unsigned pk = (unsigned)f2b(acc0) | ((unsigned)f2b(acc1) << 16);
            *(unsigned*)(out + bq * DD + h * DH + dh2 * 2) = pk;
        }
    }
}

// ------------------------------------------------------------------
// LayerNorm over last dim 256; one wave per row.
// bfout (optional): bf16 copy of the LN output, with optional q_pos added.
// ------------------------------------------------------------------
__global__ __launch_bounds__(256) void ln_kernel(
    const float* __restrict__ x, const float* __restrict__ g,
    const float* __restrict__ bta, float* __restrict__ out,
    ushort* __restrict__ bfout, const float* __restrict__ pos)
{
    int row = blockIdx.x * 4 + (threadIdx.x >> 6);
    int lane = threadIdx.x & 63;
    const float* xp = x + (size_t)row * DD;
    float vals[4];
    float s = 0.f, s2 = 0.f;
#pragma unroll
    for (int j = 0; j < 4; ++j) {
        float vv = xp[j * 64 + lane];
        vals[j] = vv;
        s += vv; s2 += vv * vv;
    }
#pragma unroll
    for (int o = 32; o > 0; o >>= 1) {
        s  += __shfl_xor(s, o);
        s2 += __shfl_xor(s2, o);
    }
    float m = s * (1.f / DD);
    float var = s2 * (1.f / DD) - m * m;
    float r = rsqrtf(var + 1e-5f);
#pragma unroll
    for (int j = 0; j < 4; ++j) {
        int d = j * 64 + lane;
        float val = (vals[j] - m) * r * g[d] + bta[d];
        out[(size_t)row * DD + d] = val;
        if (bfout) {
            float bv = pos ? val + pos[(size_t)row * DD + d] : val;
            bfout[(size_t)row * DD + d] = f2b(bv);
        }
    }
}

// ------------------------------------------------------------------
extern "C" void kernel_launch(void* const* d_in, const int* in_sizes, int n_in,
                              void* d_out, int out_size, void* d_ws, size_t ws_size,
                              hipStream_t stream)
{
    const float* src[4]  = {(const float*)d_in[0], (const float*)d_in[3],
                            (const float*)d_in[6], (const float*)d_in[9]};
    const float* q_feat  = (const float*)d_in[12];
    const float* q_pos   = (const float*)d_in[13];
    const float* q_ref   = (const float*)d_in[14];
    const float* so_w = (const float*)d_in[16];
    const float* so_b = (const float*)d_in[17];
    const float* aw_w = (const float*)d_in[18];
    const float* aw_b = (const float*)d_in[19];
    const float* vp_w = (const float*)d_in[20];
    const float* vp_b = (const float*)d_in[21];
    const float* op_w = (const float*)d_in[22];
    const float* op_b = (const float*)d_in[23];
    const float* n1_g = (const float*)d_in[24];
    const float* n1_b = (const float*)d_in[25];
    const float* l1_w = (const float*)d_in[26];
    const float* l1_b = (const float*)d_in[27];
    const float* l2_w = (const float*)d_in[28];
    const float* l2_b = (const float*)d_in[29];
    const float* n2_g = (const float*)d_in[30];
    const float* n2_b = (const float*)d_in[31];

    char* p = (char*)d_ws;
    auto alloc = [&](size_t bytes) { char* r = p; p += (bytes + 255) & ~255ULL; return r; };

    ushort* src_flat = (ushort*)alloc((size_t)BB * SS * DD * 2);
    ushort* v_buf    = (ushort*)alloc((size_t)BB * NH * SS * DH * 2);
    ushort* q_bf     = (ushort*)alloc((size_t)BB * NQ * DD * 2);
    float*  offs     = (float*) alloc((size_t)BB * NQ * 256 * 4);
    float*  awb      = (float*) alloc((size_t)BB * NQ * 128 * 4);
    ushort* msda_bf  = (ushort*)alloc((size_t)BB * NQ * DD * 2);
    float*  tmp      = (float*) alloc((size_t)BB * NQ * DD * 4);
    ushort* hbuf     = (ushort*)alloc((size_t)BB * NQ * DFF * 2);
    ushort* qf_bf    = (ushort*)alloc((size_t)BB * NQ * DD * 2);
    ushort* w_so     = (ushort*)alloc((size_t)NL * 256 * 256 * 2);
    ushort* w_aw     = (ushort*)alloc((size_t)NL * 128 * 256 * 2);
    ushort* w_vp     = (ushort*)alloc((size_t)NL * 256 * 256 * 2);
    ushort* w_op     = (ushort*)alloc((size_t)NL * 256 * 256 * 2);
    ushort* w_l1     = (ushort*)alloc((size_t)NL * DFF * 256 * 2);
    ushort* w_l2     = (ushort*)alloc((size_t)NL * 256 * DFF * 2);

    float* qf = (float*)d_out;   // residual stream lives in d_out

    // weight conversion (per launch; deterministic)
    cvt_kernel<<<(NL * 256 * 256 / 4 + 255) / 256, 256, 0, stream>>>(so_w, w_so, NL * 256 * 256 / 4);
    cvt_kernel<<<(NL * 128 * 256 / 4 + 255) / 256, 256, 0, stream>>>(aw_w, w_aw, NL * 128 * 256 / 4);
    cvt_kernel<<<(NL * 256 * 256 / 4 + 255) / 256, 256, 0, stream>>>(vp_w, w_vp, NL * 256 * 256 / 4);
    cvt_kernel<<<(NL * 256 * 256 / 4 + 255) / 256, 256, 0, stream>>>(op_w, w_op, NL * 256 * 256 / 4);
    cvt_kernel<<<(NL * DFF * 256 / 4 + 255) / 256, 256, 0, stream>>>(l1_w, w_l1, NL * DFF * 256 / 4);
    cvt_kernel<<<(NL * DFF * 256 / 4 + 255) / 256, 256, 0, stream>>>(l2_w, w_l2, NL * DFF * 256 / 4);

    // flatten sources (B,D,H,W) -> (B,S,D) bf16
    {
        int HW[4] = {16384, 4096, 1024, 256};
        int st[4] = {0, 16384, 20480, 21504};
        for (int l = 0; l < 4; ++l) {
            dim3 grid(HW[l] / 64, DD / 64, BB);
            flatten_kernel<<<grid, 256, 0, stream>>>(src[l], src_flat, HW[l], st[l]);
        }
        hipMemcpyAsync(qf, q_feat, (size_t)BB * NQ * DD * sizeof(float),
                       hipMemcpyDeviceToDevice, stream);
    }

    const int RQ = BB * NQ;       // 8192 query rows
    const int RV = BB * SS;       // 43520 value rows

    // q_bf for layer 0: bf16(q_feat + q_pos)
    add_bf_kernel<<<RQ * DD / (256 * 4), 256, 0, stream>>>(q_feat, q_pos, q_bf, RQ * DD / 4);

    for (int l = 0; l < NL; ++l) {
        const float* vp_bl = vp_b + (size_t)l * 256;
        const float* so_bl = so_b + (size_t)l * 256;
        const float* aw_bl = aw_b + (size_t)l * 128;
        const float* op_bl = op_b + (size_t)l * 256;
        const float* l1_bl = l1_b + (size_t)l * DFF;
        const float* l2_bl = l2_b + (size_t)l * 256;

        // v = src_flat @ vp_w^T + vp_b  -> (B,NH,S,DH) bf16
        gemm_bf16<256, EPI_VSC><<<dim3(RV / 128, 2), 256, 0, stream>>>(
            src_flat, w_vp + (size_t)l * 256 * 256, vp_bl, nullptr, v_buf, 256,
            nullptr, nullptr, nullptr);

        // fused q-projections: offsets (E 0..255) + attention logits (256..383)
        gemm_bf16<256, EPI_QF><<<dim3(RQ / 128, 3), 256, 0, stream>>>(
            q_bf, w_so + (size_t)l * 256 * 256, so_bl, nullptr, offs, 256,
            w_aw + (size_t)l * 128 * 256, aw_bl, awb);

        // bilinear sampling + weighted aggregation -> msda_bf (B,NQ,D)
        msda_kernel<<<(BB * NQ) / 4, 256, 0, stream>>>(v_buf, offs, awb, q_ref, msda_bf);

        // output projection + residual -> tmp; LN1 -> qf (+bf16 for FFN)
        gemm_bf16<256, EPI_RES><<<dim3(RQ / 128, 2), 256, 0, stream>>>(
            msda_bf, w_op + (size_t)l * 256 * 256, op_bl, qf, tmp, 256,
            nullptr, nullptr, nullptr);
        ln_kernel<<<RQ / 4, 256, 0, stream>>>(tmp, n1_g + l * 256, n1_b + l * 256,
                                              qf, qf_bf, nullptr);

        // FFN
        gemm_bf16<256, EPI_RELUB><<<dim3(RQ / 128, DFF / 128), 256, 0, stream>>>(
            qf_bf, w_l1 + (size_t)l * DFF * 256, l1_bl, nullptr, hbuf, DFF,
            nullptr, nullptr, nullptr);
        gemm_bf16<1024, EPI_RES><<<dim3(RQ / 128, 2), 256, 0, stream>>>(
            hbuf, w_l2 + (size_t)l * 256 * DFF, l2_bl, qf, tmp, 256,
            nullptr, nullptr, nullptr);
        // LN2 -> qf; bf16(out + q_pos) -> q_bf for next layer's projections
        ln_kernel<<<RQ / 4, 256, 0, stream>>>(tmp, n2_g + l * 256, n2_b + l * 256,
                                              qf, q_bf, q_pos);
    }

    (void)in_sizes; (void)n_in; (void)out_size; (void)ws_size;
}

// Round 8
// 598.609 us; speedup vs baseline: 3.2253x; 1.1304x over previous
//
#include <hip/hip_runtime.h>
#include <math.h>

// ---- problem constants ----
#define BB 2
#define DD 256
#define NH 8
#define DH 32
#define NPNP 4
#define LV 4
#define NQ 4096
#define NL 6
#define DFF 1024
#define SS 21760   // 128*128 + 64*64 + 32*32 + 16*16

typedef short v8s __attribute__((ext_vector_type(8)));
typedef float v4f __attribute__((ext_vector_type(4)));

__device__ __forceinline__ ushort f2b(float f) {
    union { float f; unsigned u; } v; v.f = f;
    unsigned r = v.u + 0x7fffu + ((v.u >> 16) & 1u);
    return (ushort)(r >> 16);
}

__device__ __constant__ int c_dims[4]   = {128, 64, 32, 16};
__device__ __constant__ int c_starts[4] = {0, 16384, 20480, 21504};
__device__ __constant__ int c_hw[4]     = {16384, 4096, 1024, 256};

// ------------------------------------------------------------------
// flatten all 4 levels: src_l (B, D, H, W) f32 -> src_flat (B, S, D) bf16
// grid: (340, 4, 2); x -> (level, s-block), y -> d-block, z -> b
// ------------------------------------------------------------------
__global__ __launch_bounds__(256) void flatten_all_kernel(
    const float* __restrict__ s0p, const float* __restrict__ s1p,
    const float* __restrict__ s2p, const float* __restrict__ s3p,
    ushort* __restrict__ dst)
{
    __shared__ float tile[64][65];
    int bx = blockIdx.x;
    int l, ls;
    if (bx < 256)      { l = 0; ls = bx; }
    else if (bx < 320) { l = 1; ls = bx - 256; }
    else if (bx < 336) { l = 2; ls = bx - 320; }
    else               { l = 3; ls = bx - 336; }
    const float* srcs[4] = {s0p, s1p, s2p, s3p};
    const float* src = srcs[l];
    const int HW = c_hw[l];
    const int start = c_starts[l];
    const int b  = blockIdx.z;
    const int d0 = blockIdx.y * 64;
    const int s0 = ls * 64;
    const int t  = threadIdx.x;
    const float* sp = src + ((size_t)b * DD + d0) * (size_t)HW + s0;
#pragma unroll
    for (int i = 0; i < 16; ++i) {
        int lin = i * 256 + t;
        int dl = lin >> 6, sl = lin & 63;
        tile[sl][dl] = sp[(size_t)dl * HW + sl];
    }
    __syncthreads();
    ushort* dp = dst + ((size_t)b * SS + start + s0) * DD + d0;
#pragma unroll
    for (int i = 0; i < 16; ++i) {
        int lin = i * 256 + t;
        int sl = lin >> 6, dl = lin & 63;
        dp[(size_t)sl * DD + dl] = f2b(tile[sl][dl]);
    }
}

// ------------------------------------------------------------------
// all weights f32 -> bf16 in one dispatch (uint4-group granularity)
// cumulative n4 bounds: so 98304 | aw 147456 | vp 245760 | op 344064 |
//                       l1 737280 | l2 1130496
// ------------------------------------------------------------------
__global__ __launch_bounds__(256) void cvt_all_kernel(
    const float* __restrict__ so, const float* __restrict__ aw,
    const float* __restrict__ vp, const float* __restrict__ op,
    const float* __restrict__ l1, const float* __restrict__ l2,
    ushort* __restrict__ qso, ushort* __restrict__ qaw,
    ushort* __restrict__ qvp, ushort* __restrict__ qop,
    ushort* __restrict__ ql1, ushort* __restrict__ ql2)
{
    int i = blockIdx.x * 256 + threadIdx.x;
    const float* in; ushort* out; int j;
    if (i < 98304)       { in = so; out = qso; j = i; }
    else if (i < 147456) { in = aw; out = qaw; j = i - 98304; }
    else if (i < 245760) { in = vp; out = qvp; j = i - 147456; }
    else if (i < 344064) { in = op; out = qop; j = i - 245760; }
    else if (i < 737280) { in = l1; out = ql1; j = i - 344064; }
    else                 { in = l2; out = ql2; j = i - 737280; }
    float4 x = ((const float4*)in)[j];
    uint2 pk;
    pk.x = (unsigned)f2b(x.x) | ((unsigned)f2b(x.y) << 16);
    pk.y = (unsigned)f2b(x.z) | ((unsigned)f2b(x.w) << 16);
    ((uint2*)out)[j] = pk;
}

// q = bf16(qf + q_pos)
__global__ __launch_bounds__(256) void add_bf_kernel(
    const float* __restrict__ a, const float* __restrict__ b,
    ushort* __restrict__ o, int n4)
{
    int i = blockIdx.x * 256 + threadIdx.x;
    if (i < n4) {
        float4 x = ((const float4*)a)[i];
        float4 y = ((const float4*)b)[i];
        uint2 pk;
        pk.x = (unsigned)f2b(x.x + y.x) | ((unsigned)f2b(x.y + y.y) << 16);
        pk.y = (unsigned)f2b(x.z + y.z) | ((unsigned)f2b(x.w + y.w) << 16);
        ((uint2*)o)[i] = pk;
    }
}

// ------------------------------------------------------------------
// bf16 MFMA NT GEMM: out[r,e] = sum_k A[r,k]*W[e,k] + bias[e]
// Tile BM x 128, BK=64; BM = MF*32 (MF fragments of 16 rows per wave).
// 4 waves as 2x2; wave tile (MF*16) x 64.
// LDS staged via global_load_lds(16B) with XOR chunk swizzle.
// EPI_VSC: blockIdx.z = layer; W/bias/out offset per layer; v layout (B,NH,S,DH).
// EPI_QF: E=384 fused q-proj; tile y<2 -> W/bias -> offs f32 (stride 256);
//         y==2 -> W2/bias2 -> awb f32 (stride 128).
// ------------------------------------------------------------------
enum { EPI_PLAIN = 0, EPI_RELUB = 1, EPI_RES = 2, EPI_VSC = 3, EPI_QF = 4 };

template <int K, int EPI, int MF>
__global__ __launch_bounds__(256) void gemm_bf16(
    const ushort* __restrict__ A, const ushort* __restrict__ W,
    const float* __restrict__ bias, const float* __restrict__ res,
    void* __restrict__ out, int E,
    const ushort* __restrict__ W2, const float* __restrict__ bias2,
    void* __restrict__ out2)
{
    __shared__ ushort As[MF * 32 * 64];
    __shared__ ushort Ws[128 * 64];
    const int tid  = threadIdx.x;
    const int wave = tid >> 6, lane = tid & 63;
    const size_t r0 = (size_t)blockIdx.x * (MF * 32);
    const int e0 = blockIdx.y * 128;
    const int wrow = wave >> 1, wcol = wave & 1;

    const ushort* Wbase = W;
    const float*  bbase = bias;
    void* outp = out;
    int eoff = 0;
    if (EPI == EPI_VSC) {
        const size_t z = blockIdx.z;
        Wbase = W + z * (256 * 256);
        bbase = bias + z * 256;
        outp  = (void*)((ushort*)out + z * ((size_t)BB * NH * SS * DH));
    }
    if (EPI == EPI_QF && blockIdx.y == 2) {
        Wbase = W2; bbase = bias2; eoff = 256;
    }

    v4f acc[MF][4];
#pragma unroll
    for (int m = 0; m < MF; ++m)
#pragma unroll
        for (int n = 0; n < 4; ++n)
#pragma unroll
            for (int j = 0; j < 4; ++j) acc[m][n][j] = 0.f;

    const int srow   = lane >> 3;                    // 0..7
    const int schunk = (lane & 7) ^ (srow & 7);      // inverse swizzle on source
    const ushort* Ag = A + (r0 + wave * 8 + srow) * K + schunk * 8;
    const ushort* Wg = Wbase + ((size_t)(e0 - eoff + wave * 8 + srow)) * K + schunk * 8;

    for (int k0 = 0; k0 < K; k0 += 64) {
#pragma unroll
        for (int i = 0; i < MF; ++i) {
            __builtin_amdgcn_global_load_lds(
                (const __attribute__((address_space(1))) void*)(Ag + (size_t)(i * 32) * K + k0),
                (__attribute__((address_space(3))) void*)(As + (i * 32 + wave * 8) * 64),
                16, 0, 0);
        }
#pragma unroll
        for (int i = 0; i < 4; ++i) {
            __builtin_amdgcn_global_load_lds(
                (const __attribute__((address_space(1))) void*)(Wg + (size_t)(i * 32) * K + k0),
                (__attribute__((address_space(3))) void*)(Ws + (i * 32 + wave * 8) * 64),
                16, 0, 0);
        }
        __syncthreads();

        const int rlo = lane & 15;
#pragma unroll
        for (int ks = 0; ks < 2; ++ks) {
            const int chi = ks * 4 + (lane >> 4);
            v8s af[MF], bf[4];
#pragma unroll
            for (int m = 0; m < MF; ++m) {
                int r = wrow * (MF * 16) + m * 16 + rlo;
                af[m] = *(const v8s*)((const char*)As + r * 128 + ((chi ^ (r & 7)) << 4));
            }
#pragma unroll
            for (int n = 0; n < 4; ++n) {
                int r = wcol * 64 + n * 16 + rlo;
                bf[n] = *(const v8s*)((const char*)Ws + r * 128 + ((chi ^ (r & 7)) << 4));
            }
#pragma unroll
            for (int m = 0; m < MF; ++m)
#pragma unroll
                for (int n = 0; n < 4; ++n)
                    acc[m][n] = __builtin_amdgcn_mfma_f32_16x16x32_bf16(
                        af[m], bf[n], acc[m][n], 0, 0, 0);
        }
        __syncthreads();
    }

    // epilogue: C/D layout col = lane&15, row = (lane>>4)*4 + j
    const int lrow = (lane >> 4) << 2;
    const int lcol = lane & 15;
#pragma unroll
    for (int m = 0; m < MF; ++m) {
#pragma unroll
        for (int n = 0; n < 4; ++n) {
            const int ecol = e0 + wcol * 64 + n * 16 + lcol;
            const float bv = bbase[ecol - eoff];
#pragma unroll
            for (int j = 0; j < 4; ++j) {
                const size_t row = r0 + wrow * (MF * 16) + m * 16 + lrow + j;
                float val = acc[m][n][j] + bv;
                if (EPI == EPI_RELUB) {
                    ((ushort*)outp)[row * E + ecol] = f2b(fmaxf(val, 0.f));
                } else if (EPI == EPI_VSC) {
                    int b = (int)(row / SS), s = (int)(row % SS);
                    ((ushort*)outp)[(((size_t)b * NH + (ecol >> 5)) * SS + s) * DH + (ecol & 31)]
                        = f2b(val);
                } else if (EPI == EPI_RES) {
                    ((float*)outp)[row * E + ecol] = val + res[row * E + ecol];
                } else if (EPI == EPI_QF) {
                    if (eoff == 0) ((float*)outp)[row * 256 + ecol] = val;
                    else           ((float*)out2)[row * 128 + (ecol - 256)] = val;
                } else {
                    ((float*)outp)[row * E + ecol] = val;
                }
            }
        }
    }
}

// ------------------------------------------------------------------
// MSDA sampling + aggregation, wave64 per (b,q) covering all 8 heads.
// ------------------------------------------------------------------
__global__ __launch_bounds__(256) void msda_kernel(
    const ushort* __restrict__ v, const float* __restrict__ offs,
    const float* __restrict__ awb, const float* __restrict__ qref,
    ushort* __restrict__ out)
{
    __shared__ uint2 iw[4][128][4];
    const int wid  = threadIdx.x >> 6;
    const int lane = threadIdx.x & 63;
    const int gid  = blockIdx.x * 4 + wid;     // (b,q)
    const int q = gid & (NQ - 1);
    const int b = gid >> 12;
    const size_t bq = (size_t)b * NQ + q;

    const float rx = qref[bq * 2 + 0];
    const float ry = qref[bq * 2 + 1];

#pragma unroll
    for (int it = 0; it < 2; ++it) {
        const int t = it * 64 + lane;          // task: h = t>>4, p = t&15
        const int pp = t & 15;
        const int lvl = pp >> 2;
        // softmax over this head's 16 logits (16-lane group)
        float a_raw = awb[bq * 128 + t];
        float mx = a_raw;
        mx = fmaxf(mx, __shfl_xor(mx, 1));
        mx = fmaxf(mx, __shfl_xor(mx, 2));
        mx = fmaxf(mx, __shfl_xor(mx, 4));
        mx = fmaxf(mx, __shfl_xor(mx, 8));
        float e = expf(a_raw - mx);
        float sum = e;
        sum += __shfl_xor(sum, 1);
        sum += __shfl_xor(sum, 2);
        sum += __shfl_xor(sum, 4);
        sum += __shfl_xor(sum, 8);
        const float a = e / sum;

        float2 oxy = *(const float2*)(offs + bq * 256 + t * 2);
        const int Wl = c_dims[lvl];
        const int st = c_starts[lvl];
        const float fW = (float)Wl;
        float x = fmaf(rx, fW, oxy.x) - 0.5f;
        float y = fmaf(ry, fW, oxy.y) - 0.5f;
        float x0f = floorf(x), y0f = floorf(y);
        float wx = x - x0f, wy = y - y0f;
        int x0 = (int)x0f, y0 = (int)y0f;
        const int hbase = (t >> 4) * SS;
#pragma unroll
        for (int c = 0; c < 4; ++c) {
            int dx = c & 1, dy = c >> 1;
            int xc = x0 + dx, yc = y0 + dy;
            bool valid = (xc >= 0) & (xc < Wl) & (yc >= 0) & (yc < Wl);
            int xi = min(max(xc, 0), Wl - 1);
            int yi = min(max(yc, 0), Wl - 1);
            float w = (dx ? wx : 1.f - wx) * (dy ? wy : 1.f - wy);
            uint2 tt;
            tt.x = (unsigned)((hbase + st + yi * Wl + xi) * (DH * 2));  // byte off
            tt.y = __float_as_uint(valid ? a * w : 0.f);
            iw[wid][t][c] = tt;
        }
    }
    __syncthreads();

    const int c   = lane >> 4;
    const int dh2 = lane & 15;
    const char* vbase = (const char*)(v + (size_t)b * NH * SS * DH) + dh2 * 4;
#pragma unroll
    for (int h = 0; h < NH; ++h) {
        float acc0 = 0.f, acc1 = 0.f;
#pragma unroll
        for (int p = 0; p < 16; ++p) {
            uint2 t = iw[wid][h * 16 + p][c];
            float cw = __uint_as_float(t.y);
            unsigned v2 = *(const unsigned*)(vbase + t.x);
            float lo = __uint_as_float(v2 << 16);
            float hi = __uint_as_float(v2 & 0xffff0000u);
            acc0 = fmaf(cw, lo, acc0);
            acc1 = fmaf(cw, hi, acc1);
        }
        acc0 += __shfl_xor(acc0, 16); acc0 += __shfl_xor(acc0, 32);
        acc1 += __shfl_xor(acc1, 16); acc1 += __shfl_xor(acc1, 32);
        if (lane < 16) {
            unsigned pk = (unsigned)f2b(acc0) | ((unsigned)f2b(acc1) << 16);
            *(unsigned*)(out + bq * DD + h * DH + dh2 * 2) = pk;
        }
    }
}

// ------------------------------------------------------------------
// LayerNorm over last dim 256; one wave per row.
// bfout (optional): bf16 copy of the LN output, with optional q_pos added.
// ------------------------------------------------------------------
__global__ __launch_bounds__(256) void ln_kernel(
    const float* __restrict__ x, const float* __restrict__ g,
    const float* __restrict__ bta, float* __restrict__ out,
    ushort* __restrict__ bfout, const float* __restrict__ pos)
{
    int row = blockIdx.x * 4 + (threadIdx.x >> 6);
    int lane = threadIdx.x & 63;
    const float* xp = x + (size_t)row * DD;
    float vals[4];
    float s = 0.f, s2 = 0.f;
#pragma unroll
    for (int j = 0; j < 4; ++j) {
        float vv = xp[j * 64 + lane];
        vals[j] = vv;
        s += vv; s2 += vv * vv;
    }
#pragma unroll
    for (int o = 32; o > 0; o >>= 1) {
        s  += __shfl_xor(s, o);
        s2 += __shfl_xor(s2, o);
    }
    float m = s * (1.f / DD);
    float var = s2 * (1.f / DD) - m * m;
    float r = rsqrtf(var + 1e-5f);
#pragma unroll
    for (int j = 0; j < 4; ++j) {
        int d = j * 64 + lane;
        float val = (vals[j] - m) * r * g[d] + bta[d];
        out[(size_t)row * DD + d] = val;
        if (bfout) {
            float bv = pos ? val + pos[(size_t)row * DD + d] : val;
            bfout[(size_t)row * DD + d] = f2b(bv);
        }
    }
}

// ------------------------------------------------------------------
extern "C" void kernel_launch(void* const* d_in, const int* in_sizes, int n_in,
                              void* d_out, int out_size, void* d_ws, size_t ws_size,
                              hipStream_t stream)
{
    const float* src[4]  = {(const float*)d_in[0], (const float*)d_in[3],
                            (const float*)d_in[6], (const float*)d_in[9]};
    const float* q_feat  = (const float*)d_in[12];
    const float* q_pos   = (const float*)d_in[13];
    const float* q_ref   = (const float*)d_in[14];
    const float* so_w = (const float*)d_in[16];
    const float* so_b = (const float*)d_in[17];
    const float* aw_w = (const float*)d_in[18];
    const float* aw_b = (const float*)d_in[19];
    const float* vp_w = (const float*)d_in[20];
    const float* vp_b = (const float*)d_in[21];
    const float* op_w = (const float*)d_in[22];
    const float* op_b = (const float*)d_in[23];
    const float* n1_g = (const float*)d_in[24];
    const float* n1_b = (const float*)d_in[25];
    const float* l1_w = (const float*)d_in[26];
    const float* l1_b = (const float*)d_in[27];
    const float* l2_w = (const float*)d_in[28];
    const float* l2_b = (const float*)d_in[29];
    const float* n2_g = (const float*)d_in[30];
    const float* n2_b = (const float*)d_in[31];

    char* p = (char*)d_ws;
    auto alloc = [&](size_t bytes) { char* r = p; p += (bytes + 255) & ~255ULL; return r; };

    ushort* src_flat = (ushort*)alloc((size_t)BB * SS * DD * 2);
    ushort* v_buf6   = (ushort*)alloc((size_t)NL * BB * NH * SS * DH * 2);
    ushort* q_bf     = (ushort*)alloc((size_t)BB * NQ * DD * 2);
    float*  offs     = (float*) alloc((size_t)BB * NQ * 256 * 4);
    float*  awb      = (float*) alloc((size_t)BB * NQ * 128 * 4);
    ushort* msda_bf  = (ushort*)alloc((size_t)BB * NQ * DD * 2);
    float*  tmp      = (float*) alloc((size_t)BB * NQ * DD * 4);
    ushort* hbuf     = (ushort*)alloc((size_t)BB * NQ * DFF * 2);
    ushort* qf_bf    = (ushort*)alloc((size_t)BB * NQ * DD * 2);
    ushort* w_so     = (ushort*)alloc((size_t)NL * 256 * 256 * 2);
    ushort* w_aw     = (ushort*)alloc((size_t)NL * 128 * 256 * 2);
    ushort* w_vp     = (ushort*)alloc((size_t)NL * 256 * 256 * 2);
    ushort* w_op     = (ushort*)alloc((size_t)NL * 256 * 256 * 2);
    ushort* w_l1     = (ushort*)alloc((size_t)NL * DFF * 256 * 2);
    ushort* w_l2     = (ushort*)alloc((size_t)NL * 256 * DFF * 2);

    float* qf = (float*)d_out;   // residual stream lives in d_out

    // all weight conversions, one dispatch
    cvt_all_kernel<<<4416, 256, 0, stream>>>(
        so_w, aw_w, vp_w, op_w, l1_w, l2_w,
        w_so, w_aw, w_vp, w_op, w_l1, w_l2);

    // flatten all 4 source levels, one dispatch
    flatten_all_kernel<<<dim3(340, 4, 2), 256, 0, stream>>>(
        src[0], src[1], src[2], src[3], src_flat);

    const int RQ = BB * NQ;       // 8192 query rows
    const int RV = BB * SS;       // 43520 value rows

    // q_bf for layer 0: bf16(q_feat + q_pos)
    add_bf_kernel<<<RQ * DD / (256 * 4), 256, 0, stream>>>(q_feat, q_pos, q_bf, RQ * DD / 4);

    // all 6 layers' v-projections in one dispatch (z = layer)
    gemm_bf16<256, EPI_VSC, 4><<<dim3(RV / 128, 2, NL), 256, 0, stream>>>(
        src_flat, w_vp, vp_b, nullptr, v_buf6, 256, nullptr, nullptr, nullptr);

    for (int l = 0; l < NL; ++l) {
        const float* so_bl = so_b + (size_t)l * 256;
        const float* aw_bl = aw_b + (size_t)l * 128;
        const float* op_bl = op_b + (size_t)l * 256;
        const float* l1_bl = l1_b + (size_t)l * DFF;
        const float* l2_bl = l2_b + (size_t)l * 256;

        // fused q-projections: offsets (E 0..255) + attention logits (256..383)
        gemm_bf16<256, EPI_QF, 2><<<dim3(RQ / 64, 3), 256, 0, stream>>>(
            q_bf, w_so + (size_t)l * 256 * 256, so_bl, nullptr, offs, 256,
            w_aw + (size_t)l * 128 * 256, aw_bl, awb);

        // bilinear sampling + weighted aggregation -> msda_bf (B,NQ,D)
        msda_kernel<<<(BB * NQ) / 4, 256, 0, stream>>>(
            v_buf6 + (size_t)l * BB * NH * SS * DH, offs, awb, q_ref, msda_bf);

        // output projection + residual -> tmp; LN1 -> qf (+bf16 for FFN)
        gemm_bf16<256, EPI_RES, 2><<<dim3(RQ / 64, 2), 256, 0, stream>>>(
            msda_bf, w_op + (size_t)l * 256 * 256, op_bl,
            (l == 0 ? q_feat : qf), tmp, 256, nullptr, nullptr, nullptr);
        ln_kernel<<<RQ / 4, 256, 0, stream>>>(tmp, n1_g + l * 256, n1_b + l * 256,
                                              qf, qf_bf, nullptr);

        // FFN
        gemm_bf16<256, EPI_RELUB, 4><<<dim3(RQ / 128, DFF / 128), 256, 0, stream>>>(
            qf_bf, w_l1 + (size_t)l * DFF * 256, l1_bl, nullptr, hbuf, DFF,
            nullptr, nullptr, nullptr);
        gemm_bf16<1024, EPI_RES, 2><<<dim3(RQ / 64, 2), 256, 0, stream>>>(
            hbuf, w_l2 + (size_t)l * 256 * DFF, l2_bl, qf, tmp, 256,
            nullptr, nullptr, nullptr);
        // LN2 -> qf; bf16(out + q_pos) -> q_bf for next layer's projections
        ln_kernel<<<RQ / 4, 256, 0, stream>>>(tmp, n2_g + l * 256, n2_b + l * 256,
                                              qf, q_bf, q_pos);
    }

    (void)in_sizes; (void)n_in; (void)out_size; (void)ws_size;
}

// Round 9
// 554.078 us; speedup vs baseline: 3.4846x; 1.0804x over previous
//
#include <hip/hip_runtime.h>
#include <math.h>

// ---- problem constants ----
#define BB 2
#define DD 256
#define NH 8
#define DH 32
#define NPNP 4
#define LV 4
#define NQ 4096
#define NL 6
#define DFF 1024
#define SS 21760   // 128*128 + 64*64 + 32*32 + 16*16

typedef short v8s __attribute__((ext_vector_type(8)));
typedef float v4f __attribute__((ext_vector_type(4)));

__device__ __forceinline__ ushort f2b(float f) {
    union { float f; unsigned u; } v; v.f = f;
    unsigned r = v.u + 0x7fffu + ((v.u >> 16) & 1u);
    return (ushort)(r >> 16);
}

__device__ __constant__ int c_dims[4]   = {128, 64, 32, 16};
__device__ __constant__ int c_starts[4] = {0, 16384, 20480, 21504};
__device__ __constant__ int c_hw[4]     = {16384, 4096, 1024, 256};

// ------------------------------------------------------------------
// flatten all 4 levels: src_l (B, D, H, W) f32 -> src_flat (B, S, D) bf16
// ------------------------------------------------------------------
__global__ __launch_bounds__(256) void flatten_all_kernel(
    const float* __restrict__ s0p, const float* __restrict__ s1p,
    const float* __restrict__ s2p, const float* __restrict__ s3p,
    ushort* __restrict__ dst)
{
    __shared__ float tile[64][65];
    int bx = blockIdx.x;
    int l, ls;
    if (bx < 256)      { l = 0; ls = bx; }
    else if (bx < 320) { l = 1; ls = bx - 256; }
    else if (bx < 336) { l = 2; ls = bx - 320; }
    else               { l = 3; ls = bx - 336; }
    const float* srcs[4] = {s0p, s1p, s2p, s3p};
    const float* src = srcs[l];
    const int HW = c_hw[l];
    const int start = c_starts[l];
    const int b  = blockIdx.z;
    const int d0 = blockIdx.y * 64;
    const int s0 = ls * 64;
    const int t  = threadIdx.x;
    const float* sp = src + ((size_t)b * DD + d0) * (size_t)HW + s0;
#pragma unroll
    for (int i = 0; i < 16; ++i) {
        int lin = i * 256 + t;
        int dl = lin >> 6, sl = lin & 63;
        tile[sl][dl] = sp[(size_t)dl * HW + sl];
    }
    __syncthreads();
    ushort* dp = dst + ((size_t)b * SS + start + s0) * DD + d0;
#pragma unroll
    for (int i = 0; i < 16; ++i) {
        int lin = i * 256 + t;
        int sl = lin >> 6, dl = lin & 63;
        dp[(size_t)sl * DD + dl] = f2b(tile[sl][dl]);
    }
}

// ------------------------------------------------------------------
// all weights f32 -> bf16 in one dispatch
// ------------------------------------------------------------------
__global__ __launch_bounds__(256) void cvt_all_kernel(
    const float* __restrict__ so, const float* __restrict__ aw,
    const float* __restrict__ vp, const float* __restrict__ op,
    const float* __restrict__ l1, const float* __restrict__ l2,
    ushort* __restrict__ qso, ushort* __restrict__ qaw,
    ushort* __restrict__ qvp, ushort* __restrict__ qop,
    ushort* __restrict__ ql1, ushort* __restrict__ ql2)
{
    int i = blockIdx.x * 256 + threadIdx.x;
    const float* in; ushort* out; int j;
    if (i < 98304)       { in = so; out = qso; j = i; }
    else if (i < 147456) { in = aw; out = qaw; j = i - 98304; }
    else if (i < 245760) { in = vp; out = qvp; j = i - 147456; }
    else if (i < 344064) { in = op; out = qop; j = i - 245760; }
    else if (i < 737280) { in = l1; out = ql1; j = i - 344064; }
    else                 { in = l2; out = ql2; j = i - 737280; }
    float4 x = ((const float4*)in)[j];
    uint2 pk;
    pk.x = (unsigned)f2b(x.x) | ((unsigned)f2b(x.y) << 16);
    pk.y = (unsigned)f2b(x.z) | ((unsigned)f2b(x.w) << 16);
    ((uint2*)out)[j] = pk;
}

// q = bf16(qf + q_pos)
__global__ __launch_bounds__(256) void add_bf_kernel(
    const float* __restrict__ a, const float* __restrict__ b,
    ushort* __restrict__ o, int n4)
{
    int i = blockIdx.x * 256 + threadIdx.x;
    if (i < n4) {
        float4 x = ((const float4*)a)[i];
        float4 y = ((const float4*)b)[i];
        uint2 pk;
        pk.x = (unsigned)f2b(x.x + y.x) | ((unsigned)f2b(x.y + y.y) << 16);
        pk.y = (unsigned)f2b(x.z + y.z) | ((unsigned)f2b(x.w + y.w) << 16);
        ((uint2*)o)[i] = pk;
    }
}

// ------------------------------------------------------------------
// v-projection for ALL 6 layers with A-panel resident in LDS.
// Block: 64 rows x 128 e. Stage A (64x256, 32KB) once; loop z, k staging
// only W tiles (L2-resident). Output scattered to (z, B, NH, S, DH) bf16.
// ------------------------------------------------------------------
__global__ __launch_bounds__(256) void vp_gemm_kernel(
    const ushort* __restrict__ A, const ushort* __restrict__ W,
    const float* __restrict__ bias, ushort* __restrict__ out)
{
    __shared__ ushort As[64 * 256];   // 32 KB
    __shared__ ushort Ws[128 * 64];   // 16 KB
    const int tid  = threadIdx.x;
    const int wave = tid >> 6, lane = tid & 63;
    const size_t r0 = (size_t)blockIdx.x * 64;
    const int e0 = blockIdx.y * 128;
    const int wrow = wave >> 1, wcol = wave & 1;

    // stage full A panel: lin -> (row = lin>>5, chunk cs = lin&31); src chunk
    // cs ^ (row&7) so LDS(row,cs) holds swizzled data, read with same XOR.
#pragma unroll
    for (int i = 0; i < 8; ++i) {
        int lin = i * 256 + tid;
        int row = lin >> 5;
        int cs  = lin & 31;
        int sc  = cs ^ (row & 7);
        __builtin_amdgcn_global_load_lds(
            (const __attribute__((address_space(1))) void*)(A + (r0 + row) * 256 + sc * 8),
            (__attribute__((address_space(3))) void*)(As + (size_t)lin * 8),
            16, 0, 0);
    }

    const int srow   = lane >> 3;
    const int schunk = (lane & 7) ^ (srow & 7);
    const int rlo  = lane & 15;
    const int lrow = (lane >> 4) << 2;
    const int lcol = lane & 15;

    for (int z = 0; z < NL; ++z) {
        const ushort* Wz = W + (size_t)z * 256 * 256;
        v4f acc[2][4];
#pragma unroll
        for (int m = 0; m < 2; ++m)
#pragma unroll
            for (int n = 0; n < 4; ++n)
#pragma unroll
                for (int j = 0; j < 4; ++j) acc[m][n][j] = 0.f;

        for (int k0 = 0; k0 < 256; k0 += 64) {
#pragma unroll
            for (int i = 0; i < 4; ++i) {
                __builtin_amdgcn_global_load_lds(
                    (const __attribute__((address_space(1))) void*)(
                        Wz + (size_t)(e0 + i * 32 + wave * 8 + srow) * 256 + k0 + schunk * 8),
                    (__attribute__((address_space(3))) void*)(Ws + (i * 32 + wave * 8) * 64),
                    16, 0, 0);
            }
            __syncthreads();
#pragma unroll
            for (int ks = 0; ks < 2; ++ks) {
                const int chiA = (k0 >> 3) + ks * 4 + (lane >> 4);
                const int chiW = ks * 4 + (lane >> 4);
                v8s af[2], bf[4];
#pragma unroll
                for (int m = 0; m < 2; ++m) {
                    int r = wrow * 32 + m * 16 + rlo;
                    af[m] = *(const v8s*)((const char*)As + r * 512 + ((chiA ^ (r & 7)) << 4));
                }
#pragma unroll
                for (int n = 0; n < 4; ++n) {
                    int r = wcol * 64 + n * 16 + rlo;
                    bf[n] = *(const v8s*)((const char*)Ws + r * 128 + ((chiW ^ (r & 7)) << 4));
                }
#pragma unroll
                for (int m = 0; m < 2; ++m)
#pragma unroll
                    for (int n = 0; n < 4; ++n)
                        acc[m][n] = __builtin_amdgcn_mfma_f32_16x16x32_bf16(
                            af[m], bf[n], acc[m][n], 0, 0, 0);
            }
            __syncthreads();
        }

        // epilogue: scatter to v layout (z, B, NH, S, DH) bf16
        ushort* outz = out + (size_t)z * BB * NH * SS * DH;
#pragma unroll
        for (int m = 0; m < 2; ++m) {
#pragma unroll
            for (int n = 0; n < 4; ++n) {
                const int ecol = e0 + wcol * 64 + n * 16 + lcol;
                const float bv = bias[z * 256 + ecol];
#pragma unroll
                for (int j = 0; j < 4; ++j) {
                    const size_t row = r0 + wrow * 32 + m * 16 + lrow + j;
                    int b = (int)(row / SS), s = (int)(row % SS);
                    outz[(((size_t)b * NH + (ecol >> 5)) * SS + s) * DH + (ecol & 31)]
                        = f2b(acc[m][n][j] + bv);
                }
            }
        }
    }
}

// ------------------------------------------------------------------
// bf16 MFMA NT GEMM (generic): out[r,e] = sum_k A[r,k]*W[e,k] + bias[e]
// Tile (MF*32) x 128, BK=64. Used for q-proj (EPI_QF) and FFN-l1 (RELUB).
// ------------------------------------------------------------------
enum { EPI_RELUB = 1, EPI_QF = 4 };

template <int K, int EPI, int MF>
__global__ __launch_bounds__(256) void gemm_bf16(
    const ushort* __restrict__ A, const ushort* __restrict__ W,
    const float* __restrict__ bias, void* __restrict__ out, int E,
    const ushort* __restrict__ W2, const float* __restrict__ bias2,
    void* __restrict__ out2)
{
    __shared__ ushort As[MF * 32 * 64];
    __shared__ ushort Ws[128 * 64];
    const int tid  = threadIdx.x;
    const int wave = tid >> 6, lane = tid & 63;
    const size_t r0 = (size_t)blockIdx.x * (MF * 32);
    const int e0 = blockIdx.y * 128;
    const int wrow = wave >> 1, wcol = wave & 1;

    const ushort* Wbase = W;
    const float*  bbase = bias;
    int eoff = 0;
    if (EPI == EPI_QF && blockIdx.y == 2) {
        Wbase = W2; bbase = bias2; eoff = 256;
    }

    v4f acc[MF][4];
#pragma unroll
    for (int m = 0; m < MF; ++m)
#pragma unroll
        for (int n = 0; n < 4; ++n)
#pragma unroll
            for (int j = 0; j < 4; ++j) acc[m][n][j] = 0.f;

    const int srow   = lane >> 3;
    const int schunk = (lane & 7) ^ (srow & 7);
    const ushort* Ag = A + (r0 + wave * 8 + srow) * K + schunk * 8;
    const ushort* Wg = Wbase + ((size_t)(e0 - eoff + wave * 8 + srow)) * K + schunk * 8;

    for (int k0 = 0; k0 < K; k0 += 64) {
#pragma unroll
        for (int i = 0; i < MF; ++i) {
            __builtin_amdgcn_global_load_lds(
                (const __attribute__((address_space(1))) void*)(Ag + (size_t)(i * 32) * K + k0),
                (__attribute__((address_space(3))) void*)(As + (i * 32 + wave * 8) * 64),
                16, 0, 0);
        }
#pragma unroll
        for (int i = 0; i < 4; ++i) {
            __builtin_amdgcn_global_load_lds(
                (const __attribute__((address_space(1))) void*)(Wg + (size_t)(i * 32) * K + k0),
                (__attribute__((address_space(3))) void*)(Ws + (i * 32 + wave * 8) * 64),
                16, 0, 0);
        }
        __syncthreads();

        const int rlo = lane & 15;
#pragma unroll
        for (int ks = 0; ks < 2; ++ks) {
            const int chi = ks * 4 + (lane >> 4);
            v8s af[MF], bf[4];
#pragma unroll
            for (int m = 0; m < MF; ++m) {
                int r = wrow * (MF * 16) + m * 16 + rlo;
                af[m] = *(const v8s*)((const char*)As + r * 128 + ((chi ^ (r & 7)) << 4));
            }
#pragma unroll
            for (int n = 0; n < 4; ++n) {
                int r = wcol * 64 + n * 16 + rlo;
                bf[n] = *(const v8s*)((const char*)Ws + r * 128 + ((chi ^ (r & 7)) << 4));
            }
#pragma unroll
            for (int m = 0; m < MF; ++m)
#pragma unroll
                for (int n = 0; n < 4; ++n)
                    acc[m][n] = __builtin_amdgcn_mfma_f32_16x16x32_bf16(
                        af[m], bf[n], acc[m][n], 0, 0, 0);
        }
        __syncthreads();
    }

    const int lrow = (lane >> 4) << 2;
    const int lcol = lane & 15;
#pragma unroll
    for (int m = 0; m < MF; ++m) {
#pragma unroll
        for (int n = 0; n < 4; ++n) {
            const int ecol = e0 + wcol * 64 + n * 16 + lcol;
            const float bv = bbase[ecol - eoff];
#pragma unroll
            for (int j = 0; j < 4; ++j) {
                const size_t row = r0 + wrow * (MF * 16) + m * 16 + lrow + j;
                float val = acc[m][n][j] + bv;
                if (EPI == EPI_RELUB) {
                    ((ushort*)out)[row * E + ecol] = f2b(fmaxf(val, 0.f));
                } else {  // EPI_QF
                    if (eoff == 0) ((float*)out)[row * 256 + ecol] = val;
                    else           ((float*)out2)[row * 128 + (ecol - 256)] = val;
                }
            }
        }
    }
}

// ------------------------------------------------------------------
// GEMM (8192 x 256 = A(8192xK) @ W(256xK)^T + bias + res) with LayerNorm
// fused in the epilogue. Block = 32 rows x 256 cols (full row) so LN stats
// are block-local: lane partials -> shfl_xor(1,2,4,8) -> LDS cross-wave.
// Writes f32 (residual stream) and bf16 (next-op input, optionally +pos).
// ------------------------------------------------------------------
template <int K, bool ADDPOS>
__global__ __launch_bounds__(256) void gemm_ln_kernel(
    const ushort* __restrict__ A, const ushort* __restrict__ W,
    const float* __restrict__ bias, const float* __restrict__ res,
    const float* __restrict__ g, const float* __restrict__ beta,
    float* __restrict__ outF, ushort* __restrict__ outB,
    const float* __restrict__ pos)
{
    __shared__ ushort As[32 * 64];    // 4 KB
    __shared__ ushort Ws[256 * 64];   // 32 KB
    __shared__ float rsum[2][32], rsq[2][32];
    const int tid  = threadIdx.x;
    const int wave = tid >> 6, lane = tid & 63;
    const size_t r0 = (size_t)blockIdx.x * 32;
    const int wrow = wave >> 1, wcol = wave & 1;
    const int rlo = lane & 15;

    v4f acc[8];
#pragma unroll
    for (int n = 0; n < 8; ++n)
#pragma unroll
        for (int j = 0; j < 4; ++j) acc[n][j] = 0.f;

    const int arow = tid >> 3;
    const int asc  = (tid & 7) ^ (arow & 7);

    for (int k0 = 0; k0 < K; k0 += 64) {
        __builtin_amdgcn_global_load_lds(
            (const __attribute__((address_space(1))) void*)(A + (r0 + arow) * K + k0 + asc * 8),
            (__attribute__((address_space(3))) void*)(As + (size_t)tid * 8),
            16, 0, 0);
#pragma unroll
        for (int i = 0; i < 8; ++i) {
            int lin = i * 256 + tid;
            int wr = lin >> 3;
            int wsc = (lin & 7) ^ (wr & 7);
            __builtin_amdgcn_global_load_lds(
                (const __attribute__((address_space(1))) void*)(W + (size_t)wr * K + k0 + wsc * 8),
                (__attribute__((address_space(3))) void*)(Ws + (size_t)lin * 8),
                16, 0, 0);
        }
        __syncthreads();
#pragma unroll
        for (int ks = 0; ks < 2; ++ks) {
            const int chi = ks * 4 + (lane >> 4);
            const int ra = wrow * 16 + rlo;
            v8s af = *(const v8s*)((const char*)As + ra * 128 + ((chi ^ (ra & 7)) << 4));
            v8s bf[8];
#pragma unroll
            for (int n = 0; n < 8; ++n) {
                int rb = wcol * 128 + n * 16 + rlo;
                bf[n] = *(const v8s*)((const char*)Ws + rb * 128 + ((chi ^ (rb & 7)) << 4));
            }
#pragma unroll
            for (int n = 0; n < 8; ++n)
                acc[n] = __builtin_amdgcn_mfma_f32_16x16x32_bf16(af, bf[n], acc[n], 0, 0, 0);
        }
        __syncthreads();
    }

    // epilogue: bias + residual, then LN over the 256-wide row
    const int lrow = (lane >> 4) << 2;
    const int lcol = lane & 15;
    float sums[4] = {0.f, 0.f, 0.f, 0.f};
    float sqs[4]  = {0.f, 0.f, 0.f, 0.f};
#pragma unroll
    for (int n = 0; n < 8; ++n) {
        const int ecol = wcol * 128 + n * 16 + lcol;
        const float bv = bias[ecol];
#pragma unroll
        for (int j = 0; j < 4; ++j) {
            const size_t row = r0 + wrow * 16 + lrow + j;
            float v = acc[n][j] + bv + res[row * 256 + ecol];
            acc[n][j] = v;
            sums[j] += v;
            sqs[j]  += v * v;
        }
    }
#pragma unroll
    for (int off = 1; off < 16; off <<= 1) {
#pragma unroll
        for (int j = 0; j < 4; ++j) {
            sums[j] += __shfl_xor(sums[j], off);
            sqs[j]  += __shfl_xor(sqs[j], off);
        }
    }
    if ((lane & 15) == 0) {
#pragma unroll
        for (int j = 0; j < 4; ++j) {
            int ridx = wrow * 16 + lrow + j;
            rsum[wcol][ridx] = sums[j];
            rsq[wcol][ridx]  = sqs[j];
        }
    }
    __syncthreads();
#pragma unroll
    for (int j = 0; j < 4; ++j) {
        const int ridx = wrow * 16 + lrow + j;
        const float s  = rsum[0][ridx] + rsum[1][ridx];
        const float sq = rsq[0][ridx] + rsq[1][ridx];
        const float mean = s * (1.f / 256.f);
        const float var  = sq * (1.f / 256.f) - mean * mean;
        const float rstd = rsqrtf(var + 1e-5f);
        const size_t row = r0 + wrow * 16 + lrow + j;
#pragma unroll
        for (int n = 0; n < 8; ++n) {
            const int ecol = wcol * 128 + n * 16 + lcol;
            float o = (acc[n][j] - mean) * rstd * g[ecol] + beta[ecol];
            outF[row * 256 + ecol] = o;
            float ob = ADDPOS ? (o + pos[row * 256 + ecol]) : o;
            outB[row * 256 + ecol] = f2b(ob);
        }
    }
}

// ------------------------------------------------------------------
// MSDA sampling + aggregation, wave64 per (b,q) covering all 8 heads.
// ------------------------------------------------------------------
__global__ __launch_bounds__(256) void msda_kernel(
    const ushort* __restrict__ v, const float* __restrict__ offs,
    const float* __restrict__ awb, const float* __restrict__ qref,
    ushort* __restrict__ out)
{
    __shared__ uint2 iw[4][128][4];
    const int wid  = threadIdx.x >> 6;
    const int lane = threadIdx.x & 63;
    const int gid  = blockIdx.x * 4 + wid;     // (b,q)
    const int q = gid & (NQ - 1);
    const int b = gid >> 12;
    const size_t bq = (size_t)b * NQ + q;

    const float rx = qref[bq * 2 + 0];
    const float ry = qref[bq * 2 + 1];

#pragma unroll
    for (int it = 0; it < 2; ++it) {
        const int t = it * 64 + lane;          // task: h = t>>4, p = t&15
        const int pp = t & 15;
        const int lvl = pp >> 2;
        float a_raw = awb[bq * 128 + t];
        float mx = a_raw;
        mx = fmaxf(mx, __shfl_xor(mx, 1));
        mx = fmaxf(mx, __shfl_xor(mx, 2));
        mx = fmaxf(mx, __shfl_xor(mx, 4));
        mx = fmaxf(mx, __shfl_xor(mx, 8));
        float e = expf(a_raw - mx);
        float sum = e;
        sum += __shfl_xor(sum, 1);
        sum += __shfl_xor(sum, 2);
        sum += __shfl_xor(sum, 4);
        sum += __shfl_xor(sum, 8);
        const float a = e / sum;

        float2 oxy = *(const float2*)(offs + bq * 256 + t * 2);
        const int Wl = c_dims[lvl];
        const int st = c_starts[lvl];
        const float fW = (float)Wl;
        float x = fmaf(rx, fW, oxy.x) - 0.5f;
        float y = fmaf(ry, fW, oxy.y) - 0.5f;
        float x0f = floorf(x), y0f = floorf(y);
        float wx = x - x0f, wy = y - y0f;
        int x0 = (int)x0f, y0 = (int)y0f;
        const int hbase = (t >> 4) * SS;
#pragma unroll
        for (int c = 0; c < 4; ++c) {
            int dx = c & 1, dy = c >> 1;
            int xc = x0 + dx, yc = y0 + dy;
            bool valid = (xc >= 0) & (xc < Wl) & (yc >= 0) & (yc < Wl);
            int xi = min(max(xc, 0), Wl - 1);
            int yi = min(max(yc, 0), Wl - 1);
            float w = (dx ? wx : 1.f - wx) * (dy ? wy : 1.f - wy);
            uint2 tt;
            tt.x = (unsigned)((hbase + st + yi * Wl + xi) * (DH * 2));
            tt.y = __float_as_uint(valid ? a * w : 0.f);
            iw[wid][t][c] = tt;
        }
    }
    __syncthreads();

    const int c   = lane >> 4;
    const int dh2 = lane & 15;
    const char* vbase = (const char*)(v + (size_t)b * NH * SS * DH) + dh2 * 4;
#pragma unroll
    for (int h = 0; h < NH; ++h) {
        float acc0 = 0.f, acc1 = 0.f;
#pragma unroll
        for (int p = 0; p < 16; ++p) {
            uint2 t = iw[wid][h * 16 + p][c];
            float cw = __uint_as_float(t.y);
            unsigned v2 = *(const unsigned*)(vbase + t.x);
            float lo = __uint_as_float(v2 << 16);
            float hi = __uint_as_float(v2 & 0xffff0000u);
            acc0 = fmaf(cw, lo, acc0);
            acc1 = fmaf(cw, hi, acc1);
        }
        acc0 += __shfl_xor(acc0, 16); acc0 += __shfl_xor(acc0, 32);
        acc1 += __shfl_xor(acc1, 16); acc1 += __shfl_xor(acc1, 32);
        if (lane < 16) {
            unsigned pk = (unsigned)f2b(acc0) | ((unsigned)f2b(acc1) << 16);
            *(unsigned*)(out + bq * DD + h * DH + dh2 * 2) = pk;
        }
    }
}

// ------------------------------------------------------------------
extern "C" void kernel_launch(void* const* d_in, const int* in_sizes, int n_in,
                              void* d_out, int out_size, void* d_ws, size_t ws_size,
                              hipStream_t stream)
{
    const float* src[4]  = {(const float*)d_in[0], (const float*)d_in[3],
                            (const float*)d_in[6], (const float*)d_in[9]};
    const float* q_feat  = (const float*)d_in[12];
    const float* q_pos   = (const float*)d_in[13];
    const float* q_ref   = (const float*)d_in[14];
    const float* so_w = (const float*)d_in[16];
    const float* so_b = (const float*)d_in[17];
    const float* aw_w = (const float*)d_in[18];
    const float* aw_b = (const float*)d_in[19];
    const float* vp_w = (const float*)d_in[20];
    const float* vp_b = (const float*)d_in[21];
    const float* op_w = (const float*)d_in[22];
    const float* op_b = (const float*)d_in[23];
    const float* n1_g = (const float*)d_in[24];
    const float* n1_b = (const float*)d_in[25];
    const float* l1_w = (const float*)d_in[26];
    const float* l1_b = (const float*)d_in[27];
    const float* l2_w = (const float*)d_in[28];
    const float* l2_b = (const float*)d_in[29];
    const float* n2_g = (const float*)d_in[30];
    const float* n2_b = (const float*)d_in[31];

    char* p = (char*)d_ws;
    auto alloc = [&](size_t bytes) { char* r = p; p += (bytes + 255) & ~255ULL; return r; };

    ushort* src_flat = (ushort*)alloc((size_t)BB * SS * DD * 2);
    ushort* v_buf6   = (ushort*)alloc((size_t)NL * BB * NH * SS * DH * 2);
    ushort* q_bf     = (ushort*)alloc((size_t)BB * NQ * DD * 2);
    float*  offs     = (float*) alloc((size_t)BB * NQ * 256 * 4);
    float*  awb      = (float*) alloc((size_t)BB * NQ * 128 * 4);
    ushort* msda_bf  = (ushort*)alloc((size_t)BB * NQ * DD * 2);
    ushort* hbuf     = (ushort*)alloc((size_t)BB * NQ * DFF * 2);
    ushort* qf_bf    = (ushort*)alloc((size_t)BB * NQ * DD * 2);
    ushort* w_so     = (ushort*)alloc((size_t)NL * 256 * 256 * 2);
    ushort* w_aw     = (ushort*)alloc((size_t)NL * 128 * 256 * 2);
    ushort* w_vp     = (ushort*)alloc((size_t)NL * 256 * 256 * 2);
    ushort* w_op     = (ushort*)alloc((size_t)NL * 256 * 256 * 2);
    ushort* w_l1     = (ushort*)alloc((size_t)NL * DFF * 256 * 2);
    ushort* w_l2     = (ushort*)alloc((size_t)NL * 256 * DFF * 2);

    float* qf = (float*)d_out;   // residual stream lives in d_out

    cvt_all_kernel<<<4416, 256, 0, stream>>>(
        so_w, aw_w, vp_w, op_w, l1_w, l2_w,
        w_so, w_aw, w_vp, w_op, w_l1, w_l2);

    flatten_all_kernel<<<dim3(340, 4, 2), 256, 0, stream>>>(
        src[0], src[1], src[2], src[3], src_flat);

    const int RQ = BB * NQ;       // 8192 query rows
    const int RV = BB * SS;       // 43520 value rows

    // q_bf for layer 0: bf16(q_feat + q_pos)
    add_bf_kernel<<<RQ * DD / (256 * 4), 256, 0, stream>>>(q_feat, q_pos, q_bf, RQ * DD / 4);

    // all 6 layers' v-projections, A-panel staged once per block
    vp_gemm_kernel<<<dim3(RV / 64, 2), 256, 0, stream>>>(
        src_flat, w_vp, vp_b, v_buf6);

    for (int l = 0; l < NL; ++l) {
        // fused q-projections: offsets (E 0..255) + attention logits (256..383)
        gemm_bf16<256, EPI_QF, 2><<<dim3(RQ / 64, 3), 256, 0, stream>>>(
            q_bf, w_so + (size_t)l * 256 * 256, so_b + (size_t)l * 256, offs, 256,
            w_aw + (size_t)l * 128 * 256, aw_b + (size_t)l * 128, awb);

        // bilinear sampling + weighted aggregation -> msda_bf (B,NQ,D)
        msda_kernel<<<(BB * NQ) / 4, 256, 0, stream>>>(
            v_buf6 + (size_t)l * BB * NH * SS * DH, offs, awb, q_ref, msda_bf);

        // output projection + residual + LN1 (writes qf f32, qf_bf bf16)
        gemm_ln_kernel<256, false><<<RQ / 32, 256, 0, stream>>>(
            msda_bf, w_op + (size_t)l * 256 * 256, op_b + (size_t)l * 256,
            (l == 0 ? q_feat : qf), n1_g + l * 256, n1_b + l * 256,
            qf, qf_bf, nullptr);

        // FFN up + ReLU
        gemm_bf16<256, EPI_RELUB, 4><<<dim3(RQ / 128, DFF / 128), 256, 0, stream>>>(
            qf_bf, w_l1 + (size_t)l * DFF * 256, l1_b + (size_t)l * DFF, hbuf, DFF,
            nullptr, nullptr, nullptr);

        // FFN down + residual + LN2 (writes qf f32; q_bf = bf16(out + q_pos))
        gemm_ln_kernel<1024, true><<<RQ / 32, 256, 0, stream>>>(
            hbuf, w_l2 + (size_t)l * 256 * DFF, l2_b + (size_t)l * 256,
            qf, n2_g + l * 256, n2_b + l * 256,
            qf, q_bf, q_pos);
    }

    (void)in_sizes; (void)n_in; (void)out_size; (void)ws_size;
}